// Round 1
// baseline (1756.060 us; speedup 1.0000x reference)
//
#include <hip/hip_runtime.h>
#include <math.h>

#define HW 16384

// ---------------------------------------------------------------------------
// 1x1 conv as GEMM: x (N, CIN_, HW), w (Cout, CIN_), out (N, Cout, HW)
// thread = 1 pixel, 32 co accumulators; blockIdx.z = co tile
// ---------------------------------------------------------------------------
template<int CIN_>
__global__ __launch_bounds__(256) void conv1x1_kernel(
    const float* __restrict__ x, const float* __restrict__ wgt,
    float* __restrict__ out, int CoutTotal) {
  int p = blockIdx.x * 256 + threadIdx.x;
  int n = blockIdx.y;
  int co0 = blockIdx.z * 32;
  const float* xb = x + (size_t)n * CIN_ * HW + p;
  const float* wt = wgt + (size_t)co0 * CIN_;
  float acc[32];
#pragma unroll
  for (int j = 0; j < 32; ++j) acc[j] = 0.f;
  for (int ci = 0; ci < CIN_; ++ci) {
    float v = xb[(size_t)ci * HW];
#pragma unroll
    for (int j = 0; j < 32; ++j) acc[j] = fmaf(wt[(size_t)j * CIN_ + ci], v, acc[j]);
  }
  float* ob = out + ((size_t)n * CoutTotal + co0) * HW + p;
#pragma unroll
  for (int j = 0; j < 32; ++j) ob[(size_t)j * HW] = acc[j];
}

// conv2: 1x1 over the 640-channel concat [xd, out_a, out_b, out_c, out_d]
__global__ __launch_bounds__(256) void conv2_kernel(
    const float* __restrict__ xd, const float* __restrict__ oa,
    const float* __restrict__ ob, const float* __restrict__ oc,
    const float* __restrict__ od, const float* __restrict__ w2,
    float* __restrict__ t2) {
  int p = blockIdx.x * 256 + threadIdx.x;
  int n = blockIdx.y;
  int co0 = blockIdx.z * 32;
  size_t nb = (size_t)n * 128 * HW + p;
  const float* parts[5] = { xd + nb, oa + nb, ob + nb, oc + nb, od + nb };
  float acc[32];
#pragma unroll
  for (int j = 0; j < 32; ++j) acc[j] = 0.f;
#pragma unroll
  for (int pa = 0; pa < 5; ++pa) {
    const float* src = parts[pa];
    const float* wt = w2 + (size_t)co0 * 640 + pa * 128;
    for (int ci = 0; ci < 128; ++ci) {
      float v = src[(size_t)ci * HW];
#pragma unroll
      for (int j = 0; j < 32; ++j) acc[j] = fmaf(wt[(size_t)j * 640 + ci], v, acc[j]);
    }
  }
  float* op = t2 + ((size_t)n * 128 + co0) * HW + p;
#pragma unroll
  for (int j = 0; j < 32; ++j) op[(size_t)j * HW] = acc[j];
}

// ---------------------------------------------------------------------------
// GroupNorm: deterministic two-stage reduction + in-place apply (with ReLU)
// 128 (n,group) pairs always (N=4, G=32). Group data is contiguous:
// base = src + (n*32+g) * chPerG * HW
// ---------------------------------------------------------------------------
__global__ __launch_bounds__(256) void gn_part_kernel(
    const float* __restrict__ src, float* __restrict__ part, int chPerG) {
  int blk = blockIdx.x;           // grp*8 + slice
  int grp = blk >> 3, slice = blk & 7;
  int total4 = (chPerG * HW) >> 2;
  int per = total4 >> 3;
  const float4* b4 = (const float4*)(src + (size_t)grp * chPerG * HW) + (size_t)slice * per;
  float s = 0.f, ss = 0.f;
  for (int i = threadIdx.x; i < per; i += 256) {
    float4 v = b4[i];
    s  += v.x + v.y + v.z + v.w;
    ss += v.x * v.x + v.y * v.y + v.z * v.z + v.w * v.w;
  }
  __shared__ float sh[256], sh2[256];
  int tid = threadIdx.x;
  sh[tid] = s; sh2[tid] = ss;
  __syncthreads();
  for (int st = 128; st > 0; st >>= 1) {
    if (tid < st) { sh[tid] += sh[tid + st]; sh2[tid] += sh2[tid + st]; }
    __syncthreads();
  }
  if (tid == 0) { part[blk * 2] = sh[0]; part[blk * 2 + 1] = sh2[0]; }
}

__global__ void gn_final_kernel(const float* __restrict__ part,
                                float* __restrict__ stats, int chPerG) {
  int g = threadIdx.x;  // 128 (n,group) pairs
  float s = 0.f, ss = 0.f;
#pragma unroll
  for (int i = 0; i < 8; ++i) { s += part[(g * 8 + i) * 2]; ss += part[(g * 8 + i) * 2 + 1]; }
  float inv = 1.f / (float)(chPerG * HW);
  float mean = s * inv;
  float var = ss * inv - mean * mean;
  stats[2 * g] = mean;
  stats[2 * g + 1] = rsqrtf(var + 1e-5f);
}

__global__ __launch_bounds__(256) void gn_apply_kernel(
    float* __restrict__ t, const float* __restrict__ stats,
    const float* __restrict__ gamma, const float* __restrict__ beta,
    int C, int chPerG) {
  unsigned i4 = blockIdx.x * 256u + threadIdx.x;
  unsigned e = i4 * 4u;
  unsigned c = (e >> 14) % (unsigned)C;
  unsigned n = e / ((unsigned)C * HW);
  unsigned g = c / (unsigned)chPerG;
  unsigned sg = n * 32u + g;
  float mean = stats[2 * sg], rstd = stats[2 * sg + 1];
  float scale = rstd * gamma[c];
  float shift = beta[c] - mean * scale;
  float4* tp = (float4*)t;
  float4 v = tp[i4];
  v.x = fmaxf(fmaf(v.x, scale, shift), 0.f);
  v.y = fmaxf(fmaf(v.y, scale, shift), 0.f);
  v.z = fmaxf(fmaf(v.z, scale, shift), 0.f);
  v.w = fmaxf(fmaf(v.w, scale, shift), 0.f);
  tp[i4] = v;
}

// ---------------------------------------------------------------------------
// Dynamic filter: f = softmax(conv3x3_dil(xd, wcat), over 9 taps)
// thread = 1 pixel; 9 accumulators; 81 FMA per 9 tap loads per ci
// wcat layout (9, 128, 3, 3)
// ---------------------------------------------------------------------------
__global__ __launch_bounds__(256) void dynfilter_kernel(
    const float* __restrict__ xd, const float* __restrict__ wcat,
    float* __restrict__ f, int d) {
  int p = blockIdx.x * 256 + threadIdx.x;
  int n = blockIdx.y;
  int h = p >> 7, w0 = p & 127;
  int offs[9];
  float mask[9];
#pragma unroll
  for (int i = 0; i < 3; ++i) {
    int hh = h + (i - 1) * d;
    bool vh = (hh >= 0) && (hh < 128);
    int hc = min(max(hh, 0), 127);
#pragma unroll
    for (int j = 0; j < 3; ++j) {
      int ww = w0 + (j - 1) * d;
      bool vw = (ww >= 0) && (ww < 128);
      int wc = min(max(ww, 0), 127);
      offs[i * 3 + j] = hc * 128 + wc;
      mask[i * 3 + j] = (vh && vw) ? 1.f : 0.f;
    }
  }
  const float* xb = xd + (size_t)n * 128 * HW;
  float acc[9];
#pragma unroll
  for (int k = 0; k < 9; ++k) acc[k] = 0.f;
  for (int ci = 0; ci < 128; ++ci) {
    const float* xc = xb + (size_t)ci * HW;
    float tv[9];
#pragma unroll
    for (int t = 0; t < 9; ++t) tv[t] = mask[t] * xc[offs[t]];
#pragma unroll
    for (int k = 0; k < 9; ++k) {
      const float* wk = wcat + ((size_t)(k * 128 + ci)) * 9;
#pragma unroll
      for (int t = 0; t < 9; ++t) acc[k] = fmaf(wk[t], tv[t], acc[k]);
    }
  }
  // softmax over the 9 taps
  float m = acc[0];
#pragma unroll
  for (int k = 1; k < 9; ++k) m = fmaxf(m, acc[k]);
  float s = 0.f;
#pragma unroll
  for (int k = 0; k < 9; ++k) { acc[k] = expf(acc[k] - m); s += acc[k]; }
  float inv = 1.f / s;
  float* fb = f + (size_t)n * 9 * HW + p;
#pragma unroll
  for (int k = 0; k < 9; ++k) fb[(size_t)k * HW] = acc[k] * inv;
}

// out_d[c, p] = sum_k f[k, p] * xd_padded[c, p + tapoffset(k)]
__global__ __launch_bounds__(256) void dynapply_kernel(
    const float* __restrict__ xd, const float* __restrict__ f,
    float* __restrict__ outb, int d) {
  int p = blockIdx.x * 256 + threadIdx.x;
  int n = blockIdx.y;
  int ci0 = blockIdx.z * 32;
  int h = p >> 7, w0 = p & 127;
  int offs[9];
  float fv[9];
#pragma unroll
  for (int i = 0; i < 3; ++i) {
    int hh = h + (i - 1) * d;
    bool vh = (hh >= 0) && (hh < 128);
    int hc = min(max(hh, 0), 127);
#pragma unroll
    for (int j = 0; j < 3; ++j) {
      int ww = w0 + (j - 1) * d;
      bool vw = (ww >= 0) && (ww < 128);
      int wc = min(max(ww, 0), 127);
      offs[i * 3 + j] = hc * 128 + wc;
      float mk = (vh && vw) ? 1.f : 0.f;
      fv[i * 3 + j] = mk * f[(size_t)(n * 9 + i * 3 + j) * HW + p];
    }
  }
  const float* xb = xd + ((size_t)n * 128 + ci0) * HW;
  float* ob = outb + ((size_t)n * 128 + ci0) * HW + p;
  for (int ci = 0; ci < 32; ++ci) {
    const float* xc = xb + (size_t)ci * HW;
    float o = 0.f;
#pragma unroll
    for (int t = 0; t < 9; ++t) o = fmaf(fv[t], xc[offs[t]], o);
    ob[(size_t)ci * HW] = o;
  }
}

// ---------------------------------------------------------------------------
extern "C" void kernel_launch(void* const* d_in, const int* in_sizes, int n_in,
                              void* d_out, int out_size, void* d_ws, size_t ws_size,
                              hipStream_t stream) {
  const float* x   = (const float*)d_in[0];
  const float* w1  = (const float*)d_in[1];
  const float* g1  = (const float*)d_in[2];
  const float* b1  = (const float*)d_in[3];
  const float* wca = (const float*)d_in[4];
  const float* wcb = (const float*)d_in[5];
  const float* wcc = (const float*)d_in[6];
  const float* wcd = (const float*)d_in[7];
  const float* w2  = (const float*)d_in[8];
  const float* g2  = (const float*)d_in[9];
  const float* b2  = (const float*)d_in[10];
  const float* w3  = (const float*)d_in[11];
  const float* g3  = (const float*)d_in[12];
  const float* b3  = (const float*)d_in[13];
  float* out = (float*)d_out;

  float* ws   = (float*)d_ws;
  float* xd   = ws;                              // 4*128*HW   = 8,388,608 f
  float* outs = xd + 8388608;                    // 4 branches = 33,554,432 f
  float* fbuf = outs + 4ull * 8388608;           // 4 * 589,824 f
  float* y2   = fbuf + 4ull * 589824;            // 8,388,608 f
  float* part = y2 + 8388608;                    // 2048 f
  float* st1  = part + 2048;                     // 256 f
  float* st2  = st1 + 256;
  float* st3  = st2 + 256;

  dim3 blk(256);
  const float* wcats[4] = { wca, wcb, wcc, wcd };
  const int dils[4] = { 1, 4, 8, 12 };

  // stage 1: 1x1 conv 512->128, GN, ReLU (in place on xd)
  conv1x1_kernel<512><<<dim3(64, 4, 4), blk, 0, stream>>>(x, w1, xd, 128);
  gn_part_kernel<<<dim3(1024), blk, 0, stream>>>(xd, part, 4);
  gn_final_kernel<<<dim3(1), dim3(128), 0, stream>>>(part, st1, 4);
  gn_apply_kernel<<<dim3(8192), blk, 0, stream>>>(xd, st1, g1, b1, 128, 4);

  // four dynamic-filter branches
  for (int br = 0; br < 4; ++br)
    dynfilter_kernel<<<dim3(64, 4), blk, 0, stream>>>(
        xd, wcats[br], fbuf + (size_t)br * 589824, dils[br]);
  for (int br = 0; br < 4; ++br)
    dynapply_kernel<<<dim3(64, 4, 4), blk, 0, stream>>>(
        xd, fbuf + (size_t)br * 589824, outs + (size_t)br * 8388608, dils[br]);

  // stage 2: 1x1 conv 640->128 over virtual concat, GN, ReLU
  conv2_kernel<<<dim3(64, 4, 4), blk, 0, stream>>>(
      xd, outs, outs + 8388608, outs + 2ull * 8388608, outs + 3ull * 8388608, w2, y2);
  gn_part_kernel<<<dim3(1024), blk, 0, stream>>>(y2, part, 4);
  gn_final_kernel<<<dim3(1), dim3(128), 0, stream>>>(part, st2, 4);
  gn_apply_kernel<<<dim3(8192), blk, 0, stream>>>(y2, st2, g2, b2, 128, 4);

  // stage 3: 1x1 conv 128->512 into d_out, GN, ReLU (in place)
  conv1x1_kernel<128><<<dim3(64, 4, 16), blk, 0, stream>>>(y2, w3, out, 512);
  gn_part_kernel<<<dim3(1024), blk, 0, stream>>>(out, part, 16);
  gn_final_kernel<<<dim3(1), dim3(128), 0, stream>>>(part, st3, 16);
  gn_apply_kernel<<<dim3(32768), blk, 0, stream>>>(out, st3, g3, b3, 512, 16);
}

// Round 2
// 1348.204 us; speedup vs baseline: 1.3025x; 1.3025x over previous
//
#include <hip/hip_runtime.h>
#include <math.h>

#define HW 16384

__device__ __forceinline__ float4 f4fma(float a, float4 b, float4 c) {
  return make_float4(fmaf(a, b.x, c.x), fmaf(a, b.y, c.y),
                     fmaf(a, b.z, c.z), fmaf(a, b.w, c.w));
}
__device__ __forceinline__ float4 f4fma4(float4 a, float4 b, float4 c) {
  return make_float4(fmaf(a.x, b.x, c.x), fmaf(a.y, b.y, c.y),
                     fmaf(a.z, b.z, c.z), fmaf(a.w, b.w, c.w));
}
__device__ __forceinline__ float4 f4scale(float4 v, float m) {
  return make_float4(v.x * m, v.y * m, v.z * m, v.w * m);
}

// ---------------------------------------------------------------------------
// 1x1 conv as GEMM, float4 pixels: thread = 4 pixels, 32 co accumulators
// ---------------------------------------------------------------------------
template<int CIN_>
__global__ __launch_bounds__(256) void conv1x1_kernel(
    const float* __restrict__ x, const float* __restrict__ wgt,
    float* __restrict__ out, int CoutTotal) {
  int q = blockIdx.x * 256 + threadIdx.x;          // quad index within image
  int n = blockIdx.y;
  int co0 = blockIdx.z * 32;
  const float4* xb = (const float4*)(x + (size_t)n * CIN_ * HW) + q;
  const float* wt = wgt + (size_t)co0 * CIN_;
  float4 acc[32];
#pragma unroll
  for (int j = 0; j < 32; ++j) acc[j] = make_float4(0.f, 0.f, 0.f, 0.f);
#pragma unroll 2
  for (int ci = 0; ci < CIN_; ++ci) {
    float4 v = xb[(size_t)ci * (HW / 4)];
#pragma unroll
    for (int j = 0; j < 32; ++j)
      acc[j] = f4fma(wt[(size_t)j * CIN_ + ci], v, acc[j]);
  }
  float4* ob = (float4*)(out + ((size_t)n * CoutTotal + co0) * HW) + q;
#pragma unroll
  for (int j = 0; j < 32; ++j) ob[(size_t)j * (HW / 4)] = acc[j];
}

// conv2: 1x1 over the 640-channel virtual concat [xd, oa, ob, oc, od]
__global__ __launch_bounds__(256) void conv2_kernel(
    const float* __restrict__ xd, const float* __restrict__ oa,
    const float* __restrict__ ob, const float* __restrict__ oc,
    const float* __restrict__ od, const float* __restrict__ w2,
    float* __restrict__ t2) {
  int q = blockIdx.x * 256 + threadIdx.x;
  int n = blockIdx.y;
  int co0 = blockIdx.z * 32;
  size_t nb = (size_t)n * 128 * HW;
  const float4* parts[5] = {
    (const float4*)(xd + nb) + q, (const float4*)(oa + nb) + q,
    (const float4*)(ob + nb) + q, (const float4*)(oc + nb) + q,
    (const float4*)(od + nb) + q };
  float4 acc[32];
#pragma unroll
  for (int j = 0; j < 32; ++j) acc[j] = make_float4(0.f, 0.f, 0.f, 0.f);
#pragma unroll
  for (int pa = 0; pa < 5; ++pa) {
    const float4* src = parts[pa];
    const float* wt = w2 + (size_t)co0 * 640 + pa * 128;
#pragma unroll 2
    for (int ci = 0; ci < 128; ++ci) {
      float4 v = src[(size_t)ci * (HW / 4)];
#pragma unroll
      for (int j = 0; j < 32; ++j)
        acc[j] = f4fma(wt[(size_t)j * 640 + ci], v, acc[j]);
    }
  }
  float4* op = (float4*)(t2 + ((size_t)n * 128 + co0) * HW) + q;
#pragma unroll
  for (int j = 0; j < 32; ++j) op[(size_t)j * (HW / 4)] = acc[j];
}

// ---------------------------------------------------------------------------
// GroupNorm (deterministic two-stage) + fused ReLU apply
// ---------------------------------------------------------------------------
__global__ __launch_bounds__(256) void gn_part_kernel(
    const float* __restrict__ src, float* __restrict__ part, int chPerG) {
  int blk = blockIdx.x;
  int grp = blk >> 3, slice = blk & 7;
  int total4 = (chPerG * HW) >> 2;
  int per = total4 >> 3;
  const float4* b4 = (const float4*)(src + (size_t)grp * chPerG * HW) + (size_t)slice * per;
  float s = 0.f, ss = 0.f;
  for (int i = threadIdx.x; i < per; i += 256) {
    float4 v = b4[i];
    s  += v.x + v.y + v.z + v.w;
    ss += v.x * v.x + v.y * v.y + v.z * v.z + v.w * v.w;
  }
  __shared__ float sh[256], sh2[256];
  int tid = threadIdx.x;
  sh[tid] = s; sh2[tid] = ss;
  __syncthreads();
  for (int st = 128; st > 0; st >>= 1) {
    if (tid < st) { sh[tid] += sh[tid + st]; sh2[tid] += sh2[tid + st]; }
    __syncthreads();
  }
  if (tid == 0) { part[blk * 2] = sh[0]; part[blk * 2 + 1] = sh2[0]; }
}

__global__ void gn_final_kernel(const float* __restrict__ part,
                                float* __restrict__ stats, int chPerG) {
  int g = threadIdx.x;
  float s = 0.f, ss = 0.f;
#pragma unroll
  for (int i = 0; i < 8; ++i) { s += part[(g * 8 + i) * 2]; ss += part[(g * 8 + i) * 2 + 1]; }
  float inv = 1.f / (float)(chPerG * HW);
  float mean = s * inv;
  float var = ss * inv - mean * mean;
  stats[2 * g] = mean;
  stats[2 * g + 1] = rsqrtf(var + 1e-5f);
}

__global__ __launch_bounds__(256) void gn_apply_kernel(
    float* __restrict__ t, const float* __restrict__ stats,
    const float* __restrict__ gamma, const float* __restrict__ beta,
    int C, int chPerG) {
  unsigned i4 = blockIdx.x * 256u + threadIdx.x;
  unsigned e = i4 * 4u;
  unsigned c = (e >> 14) % (unsigned)C;
  unsigned n = e / ((unsigned)C * HW);
  unsigned g = c / (unsigned)chPerG;
  unsigned sg = n * 32u + g;
  float mean = stats[2 * sg], rstd = stats[2 * sg + 1];
  float scale = rstd * gamma[c];
  float shift = beta[c] - mean * scale;
  float4* tp = (float4*)t;
  float4 v = tp[i4];
  v.x = fmaxf(fmaf(v.x, scale, shift), 0.f);
  v.y = fmaxf(fmaf(v.y, scale, shift), 0.f);
  v.z = fmaxf(fmaf(v.z, scale, shift), 0.f);
  v.w = fmaxf(fmaf(v.w, scale, shift), 0.f);
  tp[i4] = v;
}

// ---------------------------------------------------------------------------
// Dynamic filter: f = softmax(conv3x3_dil(xd, wcat)); thread = 4 pixels
// ---------------------------------------------------------------------------
template<int D>
__global__ __launch_bounds__(256) void dynfilter_kernel(
    const float* __restrict__ xd, const float* __restrict__ wcat,
    float* __restrict__ f) {
  int q = blockIdx.x * 256 + threadIdx.x;     // quad index (4096 per image)
  int n = blockIdx.y;
  int p0 = q * 4;
  int h = p0 >> 7, w0 = p0 & 127;
  const float4* xb4 = (const float4*)(xd + (size_t)n * 128 * HW);

  float4 acc[9];
#pragma unroll
  for (int k = 0; k < 9; ++k) acc[k] = make_float4(0.f, 0.f, 0.f, 0.f);

  if constexpr (D % 4 == 0) {
    // all tap quads are float4-aligned; validity is uniform per quad
    int qoff[9]; float qm[9];
#pragma unroll
    for (int i = 0; i < 3; ++i) {
      int hh = h + (i - 1) * D;
      float rm = (hh >= 0 && hh < 128) ? 1.f : 0.f;
      int rb = (min(max(hh, 0), 127)) << 7;
#pragma unroll
      for (int j = 0; j < 3; ++j) {
        int ww = w0 + (j - 1) * D;
        float hm = (ww >= 0 && ww < 128) ? 1.f : 0.f;
        ww = min(max(ww, 0), 124);
        qoff[i * 3 + j] = (rb + ww) >> 2;
        qm[i * 3 + j] = rm * hm;
      }
    }
    for (int ci = 0; ci < 128; ++ci) {
      const float4* xc4 = xb4 + (size_t)ci * (HW / 4);
      float4 tv[9];
#pragma unroll
      for (int t = 0; t < 9; ++t) tv[t] = f4scale(xc4[qoff[t]], qm[t]);
#pragma unroll
      for (int k = 0; k < 9; ++k) {
        const float* wk = wcat + (size_t)(k * 128 + ci) * 9;
#pragma unroll
        for (int t = 0; t < 9; ++t) acc[k] = f4fma(wk[t], tv[t], acc[k]);
      }
    }
  } else {  // D == 1: shuffle scheme, quads at w0-4 / w0 / w0+4
    int qLp[3], qCp[3], qRp[3]; float rm[3];
#pragma unroll
    for (int i = 0; i < 3; ++i) {
      int hh = h + (i - 1);
      rm[i] = (hh >= 0 && hh < 128) ? 1.f : 0.f;
      int rb = (min(max(hh, 0), 127)) << 7;
      qLp[i] = (rb + max(w0 - 4, 0)) >> 2;
      qCp[i] = (rb + w0) >> 2;
      qRp[i] = (rb + min(w0 + 4, 124)) >> 2;
    }
    float m0 = (w0 > 0) ? 1.f : 0.f;
    float m3 = (w0 < 124) ? 1.f : 0.f;
    for (int ci = 0; ci < 128; ++ci) {
      const float4* xc4 = xb4 + (size_t)ci * (HW / 4);
      float4 tv[9];
#pragma unroll
      for (int i = 0; i < 3; ++i) {
        float4 L = xc4[qLp[i]], C = xc4[qCp[i]], R = xc4[qRp[i]];
        float r = rm[i];
        tv[i * 3 + 0] = make_float4(L.w * r * m0, C.x * r, C.y * r, C.z * r);
        tv[i * 3 + 1] = make_float4(C.x * r, C.y * r, C.z * r, C.w * r);
        tv[i * 3 + 2] = make_float4(C.y * r, C.z * r, C.w * r, R.x * r * m3);
      }
#pragma unroll
      for (int k = 0; k < 9; ++k) {
        const float* wk = wcat + (size_t)(k * 128 + ci) * 9;
#pragma unroll
        for (int t = 0; t < 9; ++t) acc[k] = f4fma(wk[t], tv[t], acc[k]);
      }
    }
  }

  // component-wise softmax over the 9 taps
  float4 mx = acc[0];
#pragma unroll
  for (int k = 1; k < 9; ++k) {
    mx.x = fmaxf(mx.x, acc[k].x); mx.y = fmaxf(mx.y, acc[k].y);
    mx.z = fmaxf(mx.z, acc[k].z); mx.w = fmaxf(mx.w, acc[k].w);
  }
  float4 s = make_float4(0.f, 0.f, 0.f, 0.f);
#pragma unroll
  for (int k = 0; k < 9; ++k) {
    acc[k].x = expf(acc[k].x - mx.x); acc[k].y = expf(acc[k].y - mx.y);
    acc[k].z = expf(acc[k].z - mx.z); acc[k].w = expf(acc[k].w - mx.w);
    s.x += acc[k].x; s.y += acc[k].y; s.z += acc[k].z; s.w += acc[k].w;
  }
  float4 inv = make_float4(1.f / s.x, 1.f / s.y, 1.f / s.z, 1.f / s.w);
  float4* fb = (float4*)(f + (size_t)n * 9 * HW) + q;
#pragma unroll
  for (int k = 0; k < 9; ++k)
    fb[(size_t)k * (HW / 4)] = make_float4(acc[k].x * inv.x, acc[k].y * inv.y,
                                           acc[k].z * inv.z, acc[k].w * inv.w);
}

// ---------------------------------------------------------------------------
// dynapply: out[ci,p] = sum_t f[t,p] * x[ci, p + delta_t]; thread = 4 pixels,
// 32 ci per thread (blockIdx.z). Masks folded into fv.
// ---------------------------------------------------------------------------
template<int D>
__global__ __launch_bounds__(256) void dynapply_kernel(
    const float* __restrict__ xd, const float* __restrict__ f,
    float* __restrict__ outb) {
  int q = blockIdx.x * 256 + threadIdx.x;
  int n = blockIdx.y;
  int ci0 = blockIdx.z * 32;
  int p0 = q * 4;
  int h = p0 >> 7, w0 = p0 & 127;

  const float4* fb = (const float4*)(f + (size_t)n * 9 * HW) + q;
  const float4* xb4 = (const float4*)(xd + ((size_t)n * 128 + ci0) * HW);
  float4* ob4 = (float4*)(outb + ((size_t)n * 128 + ci0) * HW) + q;

  if constexpr (D % 4 == 0) {
    int qoff[9];
    float4 fv[9];
#pragma unroll
    for (int i = 0; i < 3; ++i) {
      int hh = h + (i - 1) * D;
      float rm = (hh >= 0 && hh < 128) ? 1.f : 0.f;
      int rb = (min(max(hh, 0), 127)) << 7;
#pragma unroll
      for (int j = 0; j < 3; ++j) {
        int ww = w0 + (j - 1) * D;
        float hm = (ww >= 0 && ww < 128) ? 1.f : 0.f;
        ww = min(max(ww, 0), 124);
        int t = i * 3 + j;
        qoff[t] = (rb + ww) >> 2;
        fv[t] = f4scale(fb[(size_t)t * (HW / 4)], rm * hm);
      }
    }
    for (int ci = 0; ci < 32; ++ci) {
      const float4* xc4 = xb4 + (size_t)ci * (HW / 4);
      float4 o = make_float4(0.f, 0.f, 0.f, 0.f);
#pragma unroll
      for (int t = 0; t < 9; ++t) o = f4fma4(fv[t], xc4[qoff[t]], o);
      ob4[(size_t)ci * (HW / 4)] = o;
    }
  } else {  // D == 1
    int qLp[3], qCp[3], qRp[3];
    float4 fv[9];
    float m0 = (w0 > 0) ? 1.f : 0.f;
    float m3 = (w0 < 124) ? 1.f : 0.f;
#pragma unroll
    for (int i = 0; i < 3; ++i) {
      int hh = h + (i - 1);
      float rm = (hh >= 0 && hh < 128) ? 1.f : 0.f;
      int rb = (min(max(hh, 0), 127)) << 7;
      qLp[i] = (rb + max(w0 - 4, 0)) >> 2;
      qCp[i] = (rb + w0) >> 2;
      qRp[i] = (rb + min(w0 + 4, 124)) >> 2;
#pragma unroll
      for (int j = 0; j < 3; ++j) {
        int t = i * 3 + j;
        fv[t] = f4scale(fb[(size_t)t * (HW / 4)], rm);
      }
      fv[i * 3 + 0].x *= m0;
      fv[i * 3 + 2].w *= m3;
    }
    for (int ci = 0; ci < 32; ++ci) {
      const float4* xc4 = xb4 + (size_t)ci * (HW / 4);
      float4 o = make_float4(0.f, 0.f, 0.f, 0.f);
#pragma unroll
      for (int i = 0; i < 3; ++i) {
        float4 L = xc4[qLp[i]], C = xc4[qCp[i]], R = xc4[qRp[i]];
        int t = i * 3;
        o.x = fmaf(fv[t].x, L.w, o.x); o.y = fmaf(fv[t].y, C.x, o.y);
        o.z = fmaf(fv[t].z, C.y, o.z); o.w = fmaf(fv[t].w, C.z, o.w);
        o = f4fma4(fv[t + 1], C, o);
        o.x = fmaf(fv[t + 2].x, C.y, o.x); o.y = fmaf(fv[t + 2].y, C.z, o.y);
        o.z = fmaf(fv[t + 2].z, C.w, o.z); o.w = fmaf(fv[t + 2].w, R.x, o.w);
      }
      ob4[(size_t)ci * (HW / 4)] = o;
    }
  }
}

// ---------------------------------------------------------------------------
extern "C" void kernel_launch(void* const* d_in, const int* in_sizes, int n_in,
                              void* d_out, int out_size, void* d_ws, size_t ws_size,
                              hipStream_t stream) {
  const float* x   = (const float*)d_in[0];
  const float* w1  = (const float*)d_in[1];
  const float* g1  = (const float*)d_in[2];
  const float* b1  = (const float*)d_in[3];
  const float* wca = (const float*)d_in[4];
  const float* wcb = (const float*)d_in[5];
  const float* wcc = (const float*)d_in[6];
  const float* wcd = (const float*)d_in[7];
  const float* w2  = (const float*)d_in[8];
  const float* g2  = (const float*)d_in[9];
  const float* b2  = (const float*)d_in[10];
  const float* w3  = (const float*)d_in[11];
  const float* g3  = (const float*)d_in[12];
  const float* b3  = (const float*)d_in[13];
  float* out = (float*)d_out;

  float* ws   = (float*)d_ws;
  float* xd   = ws;
  float* outs = xd + 8388608;
  float* fbuf = outs + 4ull * 8388608;
  float* y2   = fbuf + 4ull * 589824;
  float* part = y2 + 8388608;
  float* st1  = part + 2048;
  float* st2  = st1 + 256;
  float* st3  = st2 + 256;

  dim3 blk(256);

  // stage 1: 1x1 conv 512->128, GN, ReLU (in place on xd)
  conv1x1_kernel<512><<<dim3(16, 4, 4), blk, 0, stream>>>(x, w1, xd, 128);
  gn_part_kernel<<<dim3(1024), blk, 0, stream>>>(xd, part, 4);
  gn_final_kernel<<<dim3(1), dim3(128), 0, stream>>>(part, st1, 4);
  gn_apply_kernel<<<dim3(8192), blk, 0, stream>>>(xd, st1, g1, b1, 128, 4);

  // four dynamic-filter branches
  dynfilter_kernel<1> <<<dim3(16, 4), blk, 0, stream>>>(xd, wca, fbuf + 0ull * 589824);
  dynfilter_kernel<4> <<<dim3(16, 4), blk, 0, stream>>>(xd, wcb, fbuf + 1ull * 589824);
  dynfilter_kernel<8> <<<dim3(16, 4), blk, 0, stream>>>(xd, wcc, fbuf + 2ull * 589824);
  dynfilter_kernel<12><<<dim3(16, 4), blk, 0, stream>>>(xd, wcd, fbuf + 3ull * 589824);

  dynapply_kernel<1> <<<dim3(16, 4, 4), blk, 0, stream>>>(xd, fbuf + 0ull * 589824, outs + 0ull * 8388608);
  dynapply_kernel<4> <<<dim3(16, 4, 4), blk, 0, stream>>>(xd, fbuf + 1ull * 589824, outs + 1ull * 8388608);
  dynapply_kernel<8> <<<dim3(16, 4, 4), blk, 0, stream>>>(xd, fbuf + 2ull * 589824, outs + 2ull * 8388608);
  dynapply_kernel<12><<<dim3(16, 4, 4), blk, 0, stream>>>(xd, fbuf + 3ull * 589824, outs + 3ull * 8388608);

  // stage 2: 1x1 conv 640->128 over virtual concat, GN, ReLU
  conv2_kernel<<<dim3(16, 4, 4), blk, 0, stream>>>(
      xd, outs, outs + 8388608, outs + 2ull * 8388608, outs + 3ull * 8388608, w2, y2);
  gn_part_kernel<<<dim3(1024), blk, 0, stream>>>(y2, part, 4);
  gn_final_kernel<<<dim3(1), dim3(128), 0, stream>>>(part, st2, 4);
  gn_apply_kernel<<<dim3(8192), blk, 0, stream>>>(y2, st2, g2, b2, 128, 4);

  // stage 3: 1x1 conv 128->512 into d_out, GN, ReLU (in place)
  conv1x1_kernel<128><<<dim3(16, 4, 16), blk, 0, stream>>>(y2, w3, out, 512);
  gn_part_kernel<<<dim3(1024), blk, 0, stream>>>(out, part, 16);
  gn_final_kernel<<<dim3(1), dim3(128), 0, stream>>>(part, st3, 16);
  gn_apply_kernel<<<dim3(32768), blk, 0, stream>>>(out, st3, g3, b3, 512, 16);
}

// Round 3
// 788.299 us; speedup vs baseline: 2.2277x; 1.7103x over previous
//
#include <hip/hip_runtime.h>
#include <math.h>

#define HW 16384

__device__ __forceinline__ float4 f4fma(float a, float4 b, float4 c) {
  return make_float4(fmaf(a, b.x, c.x), fmaf(a, b.y, c.y),
                     fmaf(a, b.z, c.z), fmaf(a, b.w, c.w));
}
__device__ __forceinline__ float4 f4fma4(float4 a, float4 b, float4 c) {
  return make_float4(fmaf(a.x, b.x, c.x), fmaf(a.y, b.y, c.y),
                     fmaf(a.z, b.z, c.z), fmaf(a.w, b.w, c.w));
}
__device__ __forceinline__ float4 f4scale(float4 v, float m) {
  return make_float4(v.x * m, v.y * m, v.z * m, v.w * m);
}
__device__ __forceinline__ float4 f4add(float4 a, float4 b) {
  return make_float4(a.x + b.x, a.y + b.y, a.z + b.z, a.w + b.w);
}

// ---------------------------------------------------------------------------
// 1x1 conv as GEMM, float4 pixels: thread = 4 pixels, CO_PER co accumulators
// ---------------------------------------------------------------------------
template<int CIN_, int CO_PER>
__global__ __launch_bounds__(256) void conv1x1_kernel(
    const float* __restrict__ x, const float* __restrict__ wgt,
    float* __restrict__ out, int CoutTotal) {
  int q = blockIdx.x * 256 + threadIdx.x;          // quad index within image
  int n = blockIdx.y;
  int co0 = blockIdx.z * CO_PER;
  const float4* xb = (const float4*)(x + (size_t)n * CIN_ * HW) + q;
  const float* wt = wgt + (size_t)co0 * CIN_;
  float4 acc[CO_PER];
#pragma unroll
  for (int j = 0; j < CO_PER; ++j) acc[j] = make_float4(0.f, 0.f, 0.f, 0.f);
#pragma unroll 4
  for (int ci = 0; ci < CIN_; ++ci) {
    float4 v = xb[(size_t)ci * (HW / 4)];
#pragma unroll
    for (int j = 0; j < CO_PER; ++j)
      acc[j] = f4fma(wt[(size_t)j * CIN_ + ci], v, acc[j]);
  }
  float4* ob = (float4*)(out + ((size_t)n * CoutTotal + co0) * HW) + q;
#pragma unroll
  for (int j = 0; j < CO_PER; ++j) ob[(size_t)j * (HW / 4)] = acc[j];
}

// conv2: 1x1 over the 640-channel virtual concat [xd, oa, ob, oc, od]
template<int CO_PER>
__global__ __launch_bounds__(256) void conv2_kernel(
    const float* __restrict__ xd, const float* __restrict__ oa,
    const float* __restrict__ ob, const float* __restrict__ oc,
    const float* __restrict__ od, const float* __restrict__ w2,
    float* __restrict__ t2) {
  int q = blockIdx.x * 256 + threadIdx.x;
  int n = blockIdx.y;
  int co0 = blockIdx.z * CO_PER;
  size_t nb = (size_t)n * 128 * HW;
  const float4* parts[5] = {
    (const float4*)(xd + nb) + q, (const float4*)(oa + nb) + q,
    (const float4*)(ob + nb) + q, (const float4*)(oc + nb) + q,
    (const float4*)(od + nb) + q };
  float4 acc[CO_PER];
#pragma unroll
  for (int j = 0; j < CO_PER; ++j) acc[j] = make_float4(0.f, 0.f, 0.f, 0.f);
#pragma unroll
  for (int pa = 0; pa < 5; ++pa) {
    const float4* src = parts[pa];
    const float* wt = w2 + (size_t)co0 * 640 + pa * 128;
#pragma unroll 4
    for (int ci = 0; ci < 128; ++ci) {
      float4 v = src[(size_t)ci * (HW / 4)];
#pragma unroll
      for (int j = 0; j < CO_PER; ++j)
        acc[j] = f4fma(wt[(size_t)j * 640 + ci], v, acc[j]);
    }
  }
  float4* op = (float4*)(t2 + ((size_t)n * 128 + co0) * HW) + q;
#pragma unroll
  for (int j = 0; j < CO_PER; ++j) op[(size_t)j * (HW / 4)] = acc[j];
}

// ---------------------------------------------------------------------------
// GroupNorm (deterministic two-stage) + fused ReLU apply
// ---------------------------------------------------------------------------
__global__ __launch_bounds__(256) void gn_part_kernel(
    const float* __restrict__ src, float* __restrict__ part, int chPerG) {
  int blk = blockIdx.x;
  int grp = blk >> 3, slice = blk & 7;
  int total4 = (chPerG * HW) >> 2;
  int per = total4 >> 3;
  const float4* b4 = (const float4*)(src + (size_t)grp * chPerG * HW) + (size_t)slice * per;
  float s = 0.f, ss = 0.f;
  for (int i = threadIdx.x; i < per; i += 256) {
    float4 v = b4[i];
    s  += v.x + v.y + v.z + v.w;
    ss += v.x * v.x + v.y * v.y + v.z * v.z + v.w * v.w;
  }
  __shared__ float sh[256], sh2[256];
  int tid = threadIdx.x;
  sh[tid] = s; sh2[tid] = ss;
  __syncthreads();
  for (int st = 128; st > 0; st >>= 1) {
    if (tid < st) { sh[tid] += sh[tid + st]; sh2[tid] += sh2[tid + st]; }
    __syncthreads();
  }
  if (tid == 0) { part[blk * 2] = sh[0]; part[blk * 2 + 1] = sh2[0]; }
}

__global__ void gn_final_kernel(const float* __restrict__ part,
                                float* __restrict__ stats, int chPerG) {
  int g = threadIdx.x;
  float s = 0.f, ss = 0.f;
#pragma unroll
  for (int i = 0; i < 8; ++i) { s += part[(g * 8 + i) * 2]; ss += part[(g * 8 + i) * 2 + 1]; }
  float inv = 1.f / (float)(chPerG * HW);
  float mean = s * inv;
  float var = ss * inv - mean * mean;
  stats[2 * g] = mean;
  stats[2 * g + 1] = rsqrtf(var + 1e-5f);
}

__global__ __launch_bounds__(256) void gn_apply_kernel(
    float* __restrict__ t, const float* __restrict__ stats,
    const float* __restrict__ gamma, const float* __restrict__ beta,
    int C, int chPerG) {
  unsigned i4 = blockIdx.x * 256u + threadIdx.x;
  unsigned e = i4 * 4u;
  unsigned c = (e >> 14) % (unsigned)C;
  unsigned n = e / ((unsigned)C * HW);
  unsigned g = c / (unsigned)chPerG;
  unsigned sg = n * 32u + g;
  float mean = stats[2 * sg], rstd = stats[2 * sg + 1];
  float scale = rstd * gamma[c];
  float shift = beta[c] - mean * scale;
  float4* tp = (float4*)t;
  float4 v = tp[i4];
  v.x = fmaxf(fmaf(v.x, scale, shift), 0.f);
  v.y = fmaxf(fmaf(v.y, scale, shift), 0.f);
  v.z = fmaxf(fmaf(v.z, scale, shift), 0.f);
  v.w = fmaxf(fmaf(v.w, scale, shift), 0.f);
  tp[i4] = v;
}

// ---------------------------------------------------------------------------
// Dynamic filter stage A: partial conv3x3_dil over a 16-ci chunk.
// pf layout (floats): (((chunk*4 + n)*9 + k)*HW) + p
// ---------------------------------------------------------------------------
#define DF_CHUNKS 8
#define DF_CSZ 16

template<int D>
__global__ __launch_bounds__(256) void dynf_part_kernel(
    const float* __restrict__ xd, const float* __restrict__ wcat,
    float* __restrict__ pf) {
  int q = blockIdx.x * 256 + threadIdx.x;     // quad index (4096 per image)
  int n = blockIdx.y;
  int ch = blockIdx.z;                        // ci chunk
  int ci0 = ch * DF_CSZ;
  int p0 = q * 4;
  int h = p0 >> 7, w0 = p0 & 127;
  const float4* xb4 = (const float4*)(xd + ((size_t)n * 128 + ci0) * HW);

  float4 acc[9];
#pragma unroll
  for (int k = 0; k < 9; ++k) acc[k] = make_float4(0.f, 0.f, 0.f, 0.f);

  if constexpr (D % 4 == 0) {
    int qoff[9]; float qm[9];
#pragma unroll
    for (int i = 0; i < 3; ++i) {
      int hh = h + (i - 1) * D;
      float rm = (hh >= 0 && hh < 128) ? 1.f : 0.f;
      int rb = (min(max(hh, 0), 127)) << 7;
#pragma unroll
      for (int j = 0; j < 3; ++j) {
        int ww = w0 + (j - 1) * D;
        float hm = (ww >= 0 && ww < 128) ? 1.f : 0.f;
        ww = min(max(ww, 0), 124);
        qoff[i * 3 + j] = (rb + ww) >> 2;
        qm[i * 3 + j] = rm * hm;
      }
    }
    for (int ci = 0; ci < DF_CSZ; ++ci) {
      const float4* xc4 = xb4 + (size_t)ci * (HW / 4);
      float4 tv[9];
#pragma unroll
      for (int t = 0; t < 9; ++t) tv[t] = f4scale(xc4[qoff[t]], qm[t]);
#pragma unroll
      for (int k = 0; k < 9; ++k) {
        const float* wk = wcat + (size_t)(k * 128 + ci0 + ci) * 9;
#pragma unroll
        for (int t = 0; t < 9; ++t) acc[k] = f4fma(wk[t], tv[t], acc[k]);
      }
    }
  } else {  // D == 1: shuffle scheme, quads at w0-4 / w0 / w0+4
    int qLp[3], qCp[3], qRp[3]; float rm[3];
#pragma unroll
    for (int i = 0; i < 3; ++i) {
      int hh = h + (i - 1);
      rm[i] = (hh >= 0 && hh < 128) ? 1.f : 0.f;
      int rb = (min(max(hh, 0), 127)) << 7;
      qLp[i] = (rb + max(w0 - 4, 0)) >> 2;
      qCp[i] = (rb + w0) >> 2;
      qRp[i] = (rb + min(w0 + 4, 124)) >> 2;
    }
    float m0 = (w0 > 0) ? 1.f : 0.f;
    float m3 = (w0 < 124) ? 1.f : 0.f;
    for (int ci = 0; ci < DF_CSZ; ++ci) {
      const float4* xc4 = xb4 + (size_t)ci * (HW / 4);
      float4 tv[9];
#pragma unroll
      for (int i = 0; i < 3; ++i) {
        float4 L = xc4[qLp[i]], C = xc4[qCp[i]], R = xc4[qRp[i]];
        float r = rm[i];
        tv[i * 3 + 0] = make_float4(L.w * r * m0, C.x * r, C.y * r, C.z * r);
        tv[i * 3 + 1] = make_float4(C.x * r, C.y * r, C.z * r, C.w * r);
        tv[i * 3 + 2] = make_float4(C.y * r, C.z * r, C.w * r, R.x * r * m3);
      }
#pragma unroll
      for (int k = 0; k < 9; ++k) {
        const float* wk = wcat + (size_t)(k * 128 + ci0 + ci) * 9;
#pragma unroll
        for (int t = 0; t < 9; ++t) acc[k] = f4fma(wk[t], tv[t], acc[k]);
      }
    }
  }

  float4* pb = (float4*)(pf + (((size_t)ch * 4 + n) * 9) * HW) + q;
#pragma unroll
  for (int k = 0; k < 9; ++k) pb[(size_t)k * (HW / 4)] = acc[k];
}

// Stage B: reduce chunks + softmax over 9 taps -> f
__global__ __launch_bounds__(256) void dynf_reduce_kernel(
    const float* __restrict__ pf, float* __restrict__ f) {
  int q = blockIdx.x * 256 + threadIdx.x;
  int n = blockIdx.y;
  float4 acc[9];
#pragma unroll
  for (int k = 0; k < 9; ++k) acc[k] = make_float4(0.f, 0.f, 0.f, 0.f);
#pragma unroll
  for (int ch = 0; ch < DF_CHUNKS; ++ch) {
    const float4* pb = (const float4*)(pf + (((size_t)ch * 4 + n) * 9) * HW) + q;
#pragma unroll
    for (int k = 0; k < 9; ++k) acc[k] = f4add(acc[k], pb[(size_t)k * (HW / 4)]);
  }
  float4 mx = acc[0];
#pragma unroll
  for (int k = 1; k < 9; ++k) {
    mx.x = fmaxf(mx.x, acc[k].x); mx.y = fmaxf(mx.y, acc[k].y);
    mx.z = fmaxf(mx.z, acc[k].z); mx.w = fmaxf(mx.w, acc[k].w);
  }
  float4 s = make_float4(0.f, 0.f, 0.f, 0.f);
#pragma unroll
  for (int k = 0; k < 9; ++k) {
    acc[k].x = expf(acc[k].x - mx.x); acc[k].y = expf(acc[k].y - mx.y);
    acc[k].z = expf(acc[k].z - mx.z); acc[k].w = expf(acc[k].w - mx.w);
    s.x += acc[k].x; s.y += acc[k].y; s.z += acc[k].z; s.w += acc[k].w;
  }
  float4 inv = make_float4(1.f / s.x, 1.f / s.y, 1.f / s.z, 1.f / s.w);
  float4* fb = (float4*)(f + (size_t)n * 9 * HW) + q;
#pragma unroll
  for (int k = 0; k < 9; ++k)
    fb[(size_t)k * (HW / 4)] = make_float4(acc[k].x * inv.x, acc[k].y * inv.y,
                                           acc[k].z * inv.z, acc[k].w * inv.w);
}

// ---------------------------------------------------------------------------
// dynapply: out[ci,p] = sum_t f[t,p] * x[ci, p + delta_t]; thread = 4 pixels,
// 16 ci per thread (blockIdx.z). Masks folded into fv.
// ---------------------------------------------------------------------------
template<int D>
__global__ __launch_bounds__(256) void dynapply_kernel(
    const float* __restrict__ xd, const float* __restrict__ f,
    float* __restrict__ outb) {
  int q = blockIdx.x * 256 + threadIdx.x;
  int n = blockIdx.y;
  int ci0 = blockIdx.z * 16;
  int p0 = q * 4;
  int h = p0 >> 7, w0 = p0 & 127;

  const float4* fb = (const float4*)(f + (size_t)n * 9 * HW) + q;
  const float4* xb4 = (const float4*)(xd + ((size_t)n * 128 + ci0) * HW);
  float4* ob4 = (float4*)(outb + ((size_t)n * 128 + ci0) * HW) + q;

  if constexpr (D % 4 == 0) {
    int qoff[9];
    float4 fv[9];
#pragma unroll
    for (int i = 0; i < 3; ++i) {
      int hh = h + (i - 1) * D;
      float rm = (hh >= 0 && hh < 128) ? 1.f : 0.f;
      int rb = (min(max(hh, 0), 127)) << 7;
#pragma unroll
      for (int j = 0; j < 3; ++j) {
        int ww = w0 + (j - 1) * D;
        float hm = (ww >= 0 && ww < 128) ? 1.f : 0.f;
        ww = min(max(ww, 0), 124);
        int t = i * 3 + j;
        qoff[t] = (rb + ww) >> 2;
        fv[t] = f4scale(fb[(size_t)t * (HW / 4)], rm * hm);
      }
    }
    for (int ci = 0; ci < 16; ++ci) {
      const float4* xc4 = xb4 + (size_t)ci * (HW / 4);
      float4 o = make_float4(0.f, 0.f, 0.f, 0.f);
#pragma unroll
      for (int t = 0; t < 9; ++t) o = f4fma4(fv[t], xc4[qoff[t]], o);
      ob4[(size_t)ci * (HW / 4)] = o;
    }
  } else {  // D == 1
    int qLp[3], qCp[3], qRp[3];
    float4 fv[9];
    float m0 = (w0 > 0) ? 1.f : 0.f;
    float m3 = (w0 < 124) ? 1.f : 0.f;
#pragma unroll
    for (int i = 0; i < 3; ++i) {
      int hh = h + (i - 1);
      float rm = (hh >= 0 && hh < 128) ? 1.f : 0.f;
      int rb = (min(max(hh, 0), 127)) << 7;
      qLp[i] = (rb + max(w0 - 4, 0)) >> 2;
      qCp[i] = (rb + w0) >> 2;
      qRp[i] = (rb + min(w0 + 4, 124)) >> 2;
#pragma unroll
      for (int j = 0; j < 3; ++j) {
        int t = i * 3 + j;
        fv[t] = f4scale(fb[(size_t)t * (HW / 4)], rm);
      }
      fv[i * 3 + 0].x *= m0;
      fv[i * 3 + 2].w *= m3;
    }
    for (int ci = 0; ci < 16; ++ci) {
      const float4* xc4 = xb4 + (size_t)ci * (HW / 4);
      float4 o = make_float4(0.f, 0.f, 0.f, 0.f);
#pragma unroll
      for (int i = 0; i < 3; ++i) {
        float4 L = xc4[qLp[i]], C = xc4[qCp[i]], R = xc4[qRp[i]];
        int t = i * 3;
        o.x = fmaf(fv[t].x, L.w, o.x); o.y = fmaf(fv[t].y, C.x, o.y);
        o.z = fmaf(fv[t].z, C.y, o.z); o.w = fmaf(fv[t].w, C.z, o.w);
        o = f4fma4(fv[t + 1], C, o);
        o.x = fmaf(fv[t + 2].x, C.y, o.x); o.y = fmaf(fv[t + 2].y, C.z, o.y);
        o.z = fmaf(fv[t + 2].z, C.w, o.z); o.w = fmaf(fv[t + 2].w, R.x, o.w);
      }
      ob4[(size_t)ci * (HW / 4)] = o;
    }
  }
}

// ---------------------------------------------------------------------------
extern "C" void kernel_launch(void* const* d_in, const int* in_sizes, int n_in,
                              void* d_out, int out_size, void* d_ws, size_t ws_size,
                              hipStream_t stream) {
  const float* x   = (const float*)d_in[0];
  const float* w1  = (const float*)d_in[1];
  const float* g1  = (const float*)d_in[2];
  const float* b1  = (const float*)d_in[3];
  const float* wca = (const float*)d_in[4];
  const float* wcb = (const float*)d_in[5];
  const float* wcc = (const float*)d_in[6];
  const float* wcd = (const float*)d_in[7];
  const float* w2  = (const float*)d_in[8];
  const float* g2  = (const float*)d_in[9];
  const float* b2  = (const float*)d_in[10];
  const float* w3  = (const float*)d_in[11];
  const float* g3  = (const float*)d_in[12];
  const float* b3  = (const float*)d_in[13];
  float* out = (float*)d_out;

  float* ws   = (float*)d_ws;
  float* xd   = ws;                       // 8,388,608 f
  float* outs = xd + 8388608;             // 33,554,432 f (4 branches)
  float* fbuf = outs + 4ull * 8388608;    // 4 * 589,824 f
  float* y2   = fbuf + 4ull * 589824;     // 8,388,608 f
  float* part = y2 + 8388608;             // 2048 f
  float* st1  = part + 2048;
  float* st2  = st1 + 256;
  float* st3  = st2 + 256;
  // pf (dynfilter partials, 8 chunks * 4 n * 9 k * HW = 4,718,592 f / branch)
  // lives inside `outs` (dead until dynapply): 4 * 4.7M = 18.9M < 33.5M f
  float* pf   = outs;

  dim3 blk(256);

  // stage 1: 1x1 conv 512->128, GN, ReLU (in place on xd)
  conv1x1_kernel<512, 16><<<dim3(16, 4, 8), blk, 0, stream>>>(x, w1, xd, 128);
  gn_part_kernel<<<dim3(1024), blk, 0, stream>>>(xd, part, 4);
  gn_final_kernel<<<dim3(1), dim3(128), 0, stream>>>(part, st1, 4);
  gn_apply_kernel<<<dim3(8192), blk, 0, stream>>>(xd, st1, g1, b1, 128, 4);

  // dynamic filters: split-K partials, then reduce+softmax
  dynf_part_kernel<1> <<<dim3(16, 4, DF_CHUNKS), blk, 0, stream>>>(xd, wca, pf + 0ull * 4718592);
  dynf_part_kernel<4> <<<dim3(16, 4, DF_CHUNKS), blk, 0, stream>>>(xd, wcb, pf + 1ull * 4718592);
  dynf_part_kernel<8> <<<dim3(16, 4, DF_CHUNKS), blk, 0, stream>>>(xd, wcc, pf + 2ull * 4718592);
  dynf_part_kernel<12><<<dim3(16, 4, DF_CHUNKS), blk, 0, stream>>>(xd, wcd, pf + 3ull * 4718592);

  for (int br = 0; br < 4; ++br)
    dynf_reduce_kernel<<<dim3(16, 4), blk, 0, stream>>>(
        pf + (size_t)br * 4718592, fbuf + (size_t)br * 589824);

  // apply dynamic filters (pf region now dead; outs written here)
  dynapply_kernel<1> <<<dim3(16, 4, 8), blk, 0, stream>>>(xd, fbuf + 0ull * 589824, outs + 0ull * 8388608);
  dynapply_kernel<4> <<<dim3(16, 4, 8), blk, 0, stream>>>(xd, fbuf + 1ull * 589824, outs + 1ull * 8388608);
  dynapply_kernel<8> <<<dim3(16, 4, 8), blk, 0, stream>>>(xd, fbuf + 2ull * 589824, outs + 2ull * 8388608);
  dynapply_kernel<12><<<dim3(16, 4, 8), blk, 0, stream>>>(xd, fbuf + 3ull * 589824, outs + 3ull * 8388608);

  // stage 2: 1x1 conv 640->128 over virtual concat, GN, ReLU
  conv2_kernel<16><<<dim3(16, 4, 8), blk, 0, stream>>>(
      xd, outs, outs + 8388608, outs + 2ull * 8388608, outs + 3ull * 8388608, w2, y2);
  gn_part_kernel<<<dim3(1024), blk, 0, stream>>>(y2, part, 4);
  gn_final_kernel<<<dim3(1), dim3(128), 0, stream>>>(part, st2, 4);
  gn_apply_kernel<<<dim3(8192), blk, 0, stream>>>(y2, st2, g2, b2, 128, 4);

  // stage 3: 1x1 conv 128->512 into d_out, GN, ReLU (in place)
  conv1x1_kernel<128, 16><<<dim3(16, 4, 32), blk, 0, stream>>>(y2, w3, out, 512);
  gn_part_kernel<<<dim3(1024), blk, 0, stream>>>(out, part, 16);
  gn_final_kernel<<<dim3(1), dim3(128), 0, stream>>>(part, st3, 16);
  gn_apply_kernel<<<dim3(32768), blk, 0, stream>>>(out, st3, g3, b3, 512, 16);
}

// Round 4
// 691.697 us; speedup vs baseline: 2.5388x; 1.1397x over previous
//
#include <hip/hip_runtime.h>
#include <math.h>

#define HW 16384

typedef float f32x4 __attribute__((ext_vector_type(4)));
typedef __bf16 bf16x8 __attribute__((ext_vector_type(8)));
typedef unsigned short u16x4 __attribute__((ext_vector_type(4)));
typedef unsigned short u16x8 __attribute__((ext_vector_type(8)));

__device__ __forceinline__ unsigned short f2bf(float f) {
  unsigned u = __float_as_uint(f);
  u += 0x7fffu + ((u >> 16) & 1u);
  return (unsigned short)(u >> 16);
}
__device__ __forceinline__ float bf2f(unsigned short s) {
  return __uint_as_float(((unsigned)s) << 16);
}

// ---------------------------------------------------------------------------
// prep: w1,w2,w3 fp32 -> bf16 (layouts unchanged, K contiguous);
// w_r[br][tap][kt(16, zero-pad >=9)][c(128)] from w_cat (9,128,3,3)
// ---------------------------------------------------------------------------
__global__ void prep_kernel(const float* __restrict__ w1, const float* __restrict__ w2,
                            const float* __restrict__ w3,
                            const float* __restrict__ wa, const float* __restrict__ wb,
                            const float* __restrict__ wc, const float* __restrict__ wd,
                            unsigned short* __restrict__ w1b, unsigned short* __restrict__ w2b,
                            unsigned short* __restrict__ w3b, unsigned short* __restrict__ wr) {
  int idx = blockIdx.x * 256 + threadIdx.x;
  if (idx < 65536) { w1b[idx] = f2bf(w1[idx]); }
  else if (idx < 147456) { int j = idx - 65536; w2b[j] = f2bf(w2[j]); }
  else if (idx < 212992) { int j = idx - 147456; w3b[j] = f2bf(w3[j]); }
  else if (idx < 286720) {
    int j = idx - 212992;
    int br = j / 18432, rem = j % 18432;
    int tap = rem / 2048, rem2 = rem % 2048;
    int kt = rem2 / 128, c = rem2 % 128;
    const float* w = (br == 0) ? wa : (br == 1) ? wb : (br == 2) ? wc : wd;
    float v = (kt < 9) ? w[(kt * 128 + c) * 9 + tap] : 0.f;
    wr[j] = f2bf(v);
  }
}

// ---------------------------------------------------------------------------
// x (n,512,HW) fp32 -> x_t (n,HW,512) bf16, LDS-tiled 64x64 transpose
// ---------------------------------------------------------------------------
__global__ __launch_bounds__(256) void xcvt_kernel(const float* __restrict__ x,
                                                   unsigned short* __restrict__ xt) {
  __shared__ float lds[64 * 65];
  int tp = blockIdx.x, tc = blockIdx.y, n = blockIdx.z;
  int t = threadIdx.x;
  const float* xb = x + ((size_t)n * 512 + tc * 64) * HW + tp * 64;
#pragma unroll
  for (int rr = 0; rr < 4; ++rr) {
    int cl = rr * 16 + (t >> 4);
    int pl = (t & 15) * 4;
    float4 v = *(const float4*)(xb + (size_t)cl * HW + pl);
    lds[cl * 65 + pl + 0] = v.x; lds[cl * 65 + pl + 1] = v.y;
    lds[cl * 65 + pl + 2] = v.z; lds[cl * 65 + pl + 3] = v.w;
  }
  __syncthreads();
  unsigned short* xo = xt + ((size_t)n * HW + tp * 64) * 512 + tc * 64;
#pragma unroll
  for (int rr = 0; rr < 4; ++rr) {
    int pl = rr * 16 + (t >> 4);
    int cl = (t & 15) * 4;
    u16x4 o;
    o[0] = f2bf(lds[(cl + 0) * 65 + pl]); o[1] = f2bf(lds[(cl + 1) * 65 + pl]);
    o[2] = f2bf(lds[(cl + 2) * 65 + pl]); o[3] = f2bf(lds[(cl + 3) * 65 + pl]);
    *(u16x4*)(xo + (size_t)pl * 512 + cl) = o;
  }
}

// ---------------------------------------------------------------------------
// conv1/conv2 MFMA: act (n,HW,K) bf16 x W (128,K) bf16 -> out (n,HW,128) fp32
// wave = 32 pixels x 128 co; wg = 4 waves = 128 pixels
// ---------------------------------------------------------------------------
template<int K>
__global__ __launch_bounds__(256) void conv_pm_kernel(
    const unsigned short* __restrict__ act, const unsigned short* __restrict__ w,
    float* __restrict__ out) {
  int wv = threadIdx.x >> 6, lane = threadIdx.x & 63;
  int lr = lane & 15, lg = lane >> 4;
  int n = blockIdx.y;
  int p0 = blockIdx.x * 128 + wv * 32;
  const unsigned short* an = act + (size_t)n * HW * K;
  f32x4 acc[2][8];
#pragma unroll
  for (int pr = 0; pr < 2; ++pr)
#pragma unroll
    for (int cb = 0; cb < 8; ++cb) acc[pr][cb] = (f32x4){0.f, 0.f, 0.f, 0.f};
  const unsigned short* a0p = an + (size_t)(p0 + lr) * K + lg * 8;
  const unsigned short* a1p = an + (size_t)(p0 + 16 + lr) * K + lg * 8;
  const unsigned short* bp = w + (size_t)lr * K + lg * 8;
  for (int ks = 0; ks < K / 32; ++ks) {
    bf16x8 a0 = *(const bf16x8*)(a0p + ks * 32);
    bf16x8 a1 = *(const bf16x8*)(a1p + ks * 32);
#pragma unroll
    for (int cb = 0; cb < 8; ++cb) {
      bf16x8 b = *(const bf16x8*)(bp + (size_t)cb * 16 * K + ks * 32);
      acc[0][cb] = __builtin_amdgcn_mfma_f32_16x16x32_bf16(a0, b, acc[0][cb], 0, 0, 0);
      acc[1][cb] = __builtin_amdgcn_mfma_f32_16x16x32_bf16(a1, b, acc[1][cb], 0, 0, 0);
    }
  }
  float* on = out + (size_t)n * HW * 128;
#pragma unroll
  for (int pr = 0; pr < 2; ++pr)
#pragma unroll
    for (int cb = 0; cb < 8; ++cb)
#pragma unroll
      for (int r = 0; r < 4; ++r)
        on[(size_t)(p0 + pr * 16 + lg * 4 + r) * 128 + cb * 16 + lr] = acc[pr][cb][r];
}

// ---------------------------------------------------------------------------
// conv3 MFMA: W3 (512,128) x y2b (n,HW,128) -> out (n,512,HW) fp32 channel-major
// + fused GN3 partial sums (deterministic per-wg partials)
// ---------------------------------------------------------------------------
__global__ __launch_bounds__(256) void conv3_kernel(
    const unsigned short* __restrict__ y, const unsigned short* __restrict__ w3,
    float* __restrict__ out, float* __restrict__ part) {
  int wv = threadIdx.x >> 6, lane = threadIdx.x & 63;
  int lr = lane & 15, lg = lane >> 4;
  int n = blockIdx.y, zc = blockIdx.z;
  int co0 = zc * 128 + wv * 32;
  int p0 = blockIdx.x * 128;
  const unsigned short* yn = y + (size_t)n * HW * 128;
  f32x4 acc[2][8];
#pragma unroll
  for (int pr = 0; pr < 2; ++pr)
#pragma unroll
    for (int cb = 0; cb < 8; ++cb) acc[pr][cb] = (f32x4){0.f, 0.f, 0.f, 0.f};
#pragma unroll
  for (int ks = 0; ks < 4; ++ks) {
    bf16x8 a0 = *(const bf16x8*)(w3 + (size_t)(co0 + lr) * 128 + ks * 32 + lg * 8);
    bf16x8 a1 = *(const bf16x8*)(w3 + (size_t)(co0 + 16 + lr) * 128 + ks * 32 + lg * 8);
#pragma unroll
    for (int cb = 0; cb < 8; ++cb) {
      bf16x8 b = *(const bf16x8*)(yn + (size_t)(p0 + cb * 16 + lr) * 128 + ks * 32 + lg * 8);
      acc[0][cb] = __builtin_amdgcn_mfma_f32_16x16x32_bf16(a0, b, acc[0][cb], 0, 0, 0);
      acc[1][cb] = __builtin_amdgcn_mfma_f32_16x16x32_bf16(a1, b, acc[1][cb], 0, 0, 0);
    }
  }
  float* on = out + (size_t)n * 512 * HW;
  float s[2] = {0.f, 0.f}, ss[2] = {0.f, 0.f};
#pragma unroll
  for (int pr = 0; pr < 2; ++pr)
#pragma unroll
    for (int cb = 0; cb < 8; ++cb)
#pragma unroll
      for (int r = 0; r < 4; ++r) {
        float v = acc[pr][cb][r];
        on[(size_t)(co0 + pr * 16 + lg * 4 + r) * HW + p0 + cb * 16 + lr] = v;
        s[pr] += v; ss[pr] += v * v;
      }
#pragma unroll
  for (int pr = 0; pr < 2; ++pr) {
    float a = s[pr], b = ss[pr];
    for (int m = 1; m < 64; m <<= 1) { a += __shfl_xor(a, m); b += __shfl_xor(b, m); }
    if (lane == 0) {
      float* pp = part + ((((size_t)n * 4 + zc) * 128 + blockIdx.x) * 8 + wv * 2 + pr) * 2;
      pp[0] = a; pp[1] = b;
    }
  }
}

__global__ void gnf3_kernel(const float* __restrict__ part, float* __restrict__ stats) {
  int t = threadIdx.x;            // 128: n = t>>5, g = t&31
  int n = t >> 5, g = t & 31;
  int zc = g >> 3, sub = g & 7;
  float s = 0.f, ss = 0.f;
  for (int xb = 0; xb < 128; ++xb) {
    const float* pp = part + ((((size_t)n * 4 + zc) * 128 + xb) * 8 + sub) * 2;
    s += pp[0]; ss += pp[1];
  }
  float inv = 1.f / (16.f * HW);
  float mean = s * inv, var = ss * inv - mean * mean;
  stats[2 * t] = mean; stats[2 * t + 1] = rsqrtf(var + 1e-5f);
}

// ---------------------------------------------------------------------------
// GN stats (pixel-major, C=128, G=32, cpg=4): one float4 == one group's chans
// ---------------------------------------------------------------------------
__global__ __launch_bounds__(256) void gnp_pm_kernel(const float* __restrict__ src,
                                                     float* __restrict__ part) {
  int t = threadIdx.x;
  int g = t & 31, ph = t >> 5;
  int pt = blockIdx.x, n = blockIdx.y;
  const float* b = src + (size_t)n * HW * 128 + 4 * g;
  float s = 0.f, ss = 0.f;
  for (int p = pt * 2048 + ph; p < (pt + 1) * 2048; p += 8) {
    float4 v = *(const float4*)(b + (size_t)p * 128);
    s += v.x + v.y + v.z + v.w;
    ss += v.x * v.x + v.y * v.y + v.z * v.z + v.w * v.w;
  }
  __shared__ float sh[256], sh2[256];
  sh[t] = s; sh2[t] = ss; __syncthreads();
  if (t < 128) { sh[t] += sh[t + 128]; sh2[t] += sh2[t + 128]; } __syncthreads();
  if (t < 64)  { sh[t] += sh[t + 64];  sh2[t] += sh2[t + 64];  } __syncthreads();
  if (t < 32) {
    float a = sh[t] + sh[t + 32], b2 = sh2[t] + sh2[t + 32];
    float* pp = part + ((size_t)(n * 8 + pt) * 32 + t) * 2;
    pp[0] = a; pp[1] = b2;
  }
}

__global__ void gnf_pm_kernel(const float* __restrict__ part, float* __restrict__ stats) {
  int t = threadIdx.x;            // 128
  int n = t >> 5, g = t & 31;
  float s = 0.f, ss = 0.f;
#pragma unroll
  for (int pt = 0; pt < 8; ++pt) {
    const float* pp = part + ((size_t)(n * 8 + pt) * 32 + g) * 2;
    s += pp[0]; ss += pp[1];
  }
  float inv = 1.f / (4.f * HW);
  float mean = s * inv, var = ss * inv - mean * mean;
  stats[2 * t] = mean; stats[2 * t + 1] = rsqrtf(var + 1e-5f);
}

// GN apply (pixel-major) + ReLU -> bf16 dst with row stride ldd
__global__ __launch_bounds__(256) void gna_pm_kernel(
    const float* __restrict__ src, const float* __restrict__ stats,
    const float* __restrict__ gamma, const float* __restrict__ beta,
    unsigned short* __restrict__ dst, int ldd) {
  int idx = blockIdx.x * 256 + threadIdx.x;
  int g = idx & 31;
  int p = (idx >> 5) & (HW - 1);
  int n = idx >> 19;
  float4 v = *(const float4*)(src + ((size_t)n * HW + p) * 128 + 4 * g);
  int sg = n * 32 + g;
  float mean = stats[2 * sg], rstd = stats[2 * sg + 1];
  float sc0 = rstd * gamma[4 * g + 0], sc1 = rstd * gamma[4 * g + 1];
  float sc2 = rstd * gamma[4 * g + 2], sc3 = rstd * gamma[4 * g + 3];
  float sh0 = beta[4 * g + 0] - mean * sc0, sh1 = beta[4 * g + 1] - mean * sc1;
  float sh2 = beta[4 * g + 2] - mean * sc2, sh3 = beta[4 * g + 3] - mean * sc3;
  u16x4 o;
  o[0] = f2bf(fmaxf(fmaf(v.x, sc0, sh0), 0.f));
  o[1] = f2bf(fmaxf(fmaf(v.y, sc1, sh1), 0.f));
  o[2] = f2bf(fmaxf(fmaf(v.z, sc2, sh2), 0.f));
  o[3] = f2bf(fmaxf(fmaf(v.w, sc3, sh3), 0.f));
  *(u16x4*)(dst + ((size_t)n * HW + p) * ldd + 4 * g) = o;
}

// GN apply channel-major fp32 in place (stage 3), from prior rounds
__global__ __launch_bounds__(256) void gn_apply_kernel(
    float* __restrict__ t, const float* __restrict__ stats,
    const float* __restrict__ gamma, const float* __restrict__ beta,
    int C, int chPerG) {
  unsigned i4 = blockIdx.x * 256u + threadIdx.x;
  unsigned e = i4 * 4u;
  unsigned c = (e >> 14) % (unsigned)C;
  unsigned n = e / ((unsigned)C * HW);
  unsigned g = c / (unsigned)chPerG;
  unsigned sg = n * 32u + g;
  float mean = stats[2 * sg], rstd = stats[2 * sg + 1];
  float scale = rstd * gamma[c];
  float shift = beta[c] - mean * scale;
  float4* tp = (float4*)t;
  float4 v = tp[i4];
  v.x = fmaxf(fmaf(v.x, scale, shift), 0.f);
  v.y = fmaxf(fmaf(v.y, scale, shift), 0.f);
  v.z = fmaxf(fmaf(v.z, scale, shift), 0.f);
  v.w = fmaxf(fmaf(v.w, scale, shift), 0.f);
  tp[i4] = v;
}

// ---------------------------------------------------------------------------
// Fused dynamic branch: MFMA 9-tap filter conv (K=128, N=16 padded) + softmax
// (cross-lane over 16-lane groups) + weighted 9-tap gather, all bf16 I/O.
// cat (n,HW,640): reads cols 0..127 (xd), writes cols 128*(br+1)..+127.
// ---------------------------------------------------------------------------
__global__ __launch_bounds__(256) void dynfused_kernel(
    const unsigned short* __restrict__ cat, const unsigned short* __restrict__ wr,
    unsigned short* __restrict__ catw) {
  __shared__ float fl[4][64][17];
  int wv = threadIdx.x >> 6, lane = threadIdx.x & 63;
  int lr = lane & 15, lg = lane >> 4;
  int n = blockIdx.y, br = blockIdx.z;
  int d = (br == 0) ? 1 : 4 * br;
  int wp0 = (blockIdx.x * 4 + wv) * 64;
  const unsigned short* xb = cat + (size_t)n * HW * 640;
  const unsigned short* wb = wr + (size_t)br * 9 * 16 * 128;
  const bf16x8 zb = {(__bf16)0.f, (__bf16)0.f, (__bf16)0.f, (__bf16)0.f,
                     (__bf16)0.f, (__bf16)0.f, (__bf16)0.f, (__bf16)0.f};
  f32x4 acc[4];
#pragma unroll
  for (int pf = 0; pf < 4; ++pf) acc[pf] = (f32x4){0.f, 0.f, 0.f, 0.f};
  int pl[4], hh[4], wwv[4];
#pragma unroll
  for (int pf = 0; pf < 4; ++pf) {
    pl[pf] = wp0 + pf * 16 + lr;
    hh[pf] = pl[pf] >> 7; wwv[pf] = pl[pf] & 127;
  }
  for (int tap = 0; tap < 9; ++tap) {
    int dh = (tap / 3 - 1) * d, dw = (tap % 3 - 1) * d;
    int delta = dh * 128 + dw;
    bool val[4]; int sp[4];
#pragma unroll
    for (int pf = 0; pf < 4; ++pf) {
      val[pf] = ((unsigned)(hh[pf] + dh) < 128u) && ((unsigned)(wwv[pf] + dw) < 128u);
      sp[pf] = val[pf] ? pl[pf] + delta : pl[pf];
    }
    const unsigned short* wt = wb + (size_t)(tap * 16 + lr) * 128 + lg * 8;
#pragma unroll
    for (int ks = 0; ks < 4; ++ks) {
      bf16x8 b = *(const bf16x8*)(wt + ks * 32);
#pragma unroll
      for (int pf = 0; pf < 4; ++pf) {
        bf16x8 a = *(const bf16x8*)(xb + (size_t)sp[pf] * 640 + ks * 32 + lg * 8);
        if (!val[pf]) a = zb;
        acc[pf] = __builtin_amdgcn_mfma_f32_16x16x32_bf16(a, b, acc[pf], 0, 0, 0);
      }
    }
  }
  // softmax over taps (cols 0..8 of each 16-lane group), store to LDS
#pragma unroll
  for (int pf = 0; pf < 4; ++pf) {
#pragma unroll
    for (int r = 0; r < 4; ++r) {
      float v = acc[pf][r];
      float m = (lr < 9) ? v : -3.0e38f;
#pragma unroll
      for (int msk = 1; msk < 16; msk <<= 1) m = fmaxf(m, __shfl_xor(m, msk));
      float e = (lr < 9) ? expf(v - m) : 0.f;
      float su = e;
#pragma unroll
      for (int msk = 1; msk < 16; msk <<= 1) su += __shfl_xor(su, msk);
      fl[wv][pf * 16 + lg * 4 + r][lr] = e / su;
    }
  }
  __syncthreads();
  // apply: lane owns pixel wp0+lane; out[c] = sum_t f[t] * xd[p+delta_t][c]
  int myp = wp0 + lane;
  int h = myp >> 7, w = myp & 127;
  float fv[9]; const unsigned short* srow[9];
#pragma unroll
  for (int tap = 0; tap < 9; ++tap) {
    int dh = (tap / 3 - 1) * d, dw = (tap % 3 - 1) * d;
    bool v = ((unsigned)(h + dh) < 128u) && ((unsigned)(w + dw) < 128u);
    int sp = v ? myp + dh * 128 + dw : myp;
    srow[tap] = xb + (size_t)sp * 640;
    fv[tap] = v ? fl[wv][lane][tap] : 0.f;
  }
  unsigned short* orow = catw + ((size_t)n * HW + myp) * 640 + 128 * (br + 1);
#pragma unroll 4
  for (int c8 = 0; c8 < 16; ++c8) {
    float a8[8] = {0.f, 0.f, 0.f, 0.f, 0.f, 0.f, 0.f, 0.f};
#pragma unroll
    for (int tap = 0; tap < 9; ++tap) {
      u16x8 u = *(const u16x8*)(srow[tap] + c8 * 8);
      float f = fv[tap];
#pragma unroll
      for (int i = 0; i < 8; ++i) a8[i] = fmaf(f, bf2f(u[i]), a8[i]);
    }
    u16x8 o;
#pragma unroll
    for (int i = 0; i < 8; ++i) o[i] = f2bf(a8[i]);
    *(u16x8*)(orow + c8 * 8) = o;
  }
}

// ---------------------------------------------------------------------------
extern "C" void kernel_launch(void* const* d_in, const int* in_sizes, int n_in,
                              void* d_out, int out_size, void* d_ws, size_t ws_size,
                              hipStream_t stream) {
  const float* x   = (const float*)d_in[0];
  const float* w1  = (const float*)d_in[1];
  const float* g1  = (const float*)d_in[2];
  const float* b1  = (const float*)d_in[3];
  const float* wca = (const float*)d_in[4];
  const float* wcb = (const float*)d_in[5];
  const float* wcc = (const float*)d_in[6];
  const float* wcd = (const float*)d_in[7];
  const float* w2  = (const float*)d_in[8];
  const float* g2  = (const float*)d_in[9];
  const float* b2  = (const float*)d_in[10];
  const float* w3  = (const float*)d_in[11];
  const float* g3  = (const float*)d_in[12];
  const float* b3  = (const float*)d_in[13];
  float* out = (float*)d_out;

  float* ws = (float*)d_ws;
  // [0,16M) floats: x_t bf16 (32M elems); later overlaid by y2t/y2b
  unsigned short* xt  = (unsigned short*)ws;
  float* xd_t = ws + 16777216;                           // [16M,24M) fp32 (n,HW,128)
  unsigned short* cat = (unsigned short*)(ws + 25165824); // [24M,44M): (n,HW,640) bf16
  float* y2t = ws;                                        // [0,8M) fp32 (overlay x_t)
  unsigned short* y2b = (unsigned short*)(ws + 8388608);  // [8M,12M) bf16
  float* aux = ws + 46137344;                             // [44M, ...)
  unsigned short* w1b = (unsigned short*)(aux);           // 65536 bf16
  unsigned short* w2b = (unsigned short*)(aux + 32768);   // 81920 bf16
  unsigned short* w3b = (unsigned short*)(aux + 73728);   // 65536 bf16
  unsigned short* wr  = (unsigned short*)(aux + 106496);  // 73728 bf16
  float* part  = aux + 143360;                            // 2048 f
  float* part3 = aux + 145408;                            // 32768 f
  float* st1   = aux + 178176;                            // 256 f
  float* st2   = aux + 178432;
  float* st3   = aux + 178688;

  dim3 blk(256);

  prep_kernel<<<dim3(1120), blk, 0, stream>>>(w1, w2, w3, wca, wcb, wcc, wcd,
                                              w1b, w2b, w3b, wr);
  xcvt_kernel<<<dim3(256, 8, 4), blk, 0, stream>>>(x, xt);

  // stage 1: conv 512->128 (MFMA), GN, ReLU -> cat cols 0..127 (bf16)
  conv_pm_kernel<512><<<dim3(128, 4), blk, 0, stream>>>(xt, w1b, xd_t);
  gnp_pm_kernel<<<dim3(8, 4), blk, 0, stream>>>(xd_t, part);
  gnf_pm_kernel<<<dim3(1), dim3(128), 0, stream>>>(part, st1);
  gna_pm_kernel<<<dim3(8192), blk, 0, stream>>>(xd_t, st1, g1, b1, cat, 640);

  // four fused dynamic branches -> cat cols 128..639 (bf16)
  dynfused_kernel<<<dim3(64, 4, 4), blk, 0, stream>>>(cat, wr, cat);

  // stage 2: conv 640->128 (MFMA) over concat, GN, ReLU -> y2b bf16
  conv_pm_kernel<640><<<dim3(128, 4), blk, 0, stream>>>(cat, w2b, y2t);
  gnp_pm_kernel<<<dim3(8, 4), blk, 0, stream>>>(y2t, part);
  gnf_pm_kernel<<<dim3(1), dim3(128), 0, stream>>>(part, st2);
  gna_pm_kernel<<<dim3(8192), blk, 0, stream>>>(y2t, st2, g2, b2, y2b, 128);

  // stage 3: conv 128->512 (MFMA) -> d_out channel-major + fused GN3 partials
  conv3_kernel<<<dim3(128, 4, 4), blk, 0, stream>>>(y2b, w3b, out, part3);
  gnf3_kernel<<<dim3(1), dim3(128), 0, stream>>>(part3, st3);
  gn_apply_kernel<<<dim3(32768), blk, 0, stream>>>(out, st3, g3, b3, 512, 16);
}

// Round 5
// 530.308 us; speedup vs baseline: 3.3114x; 1.3043x over previous
//
#include <hip/hip_runtime.h>
#include <math.h>

#define HW 16384

typedef float f32x4 __attribute__((ext_vector_type(4)));
typedef __bf16 bf16x8 __attribute__((ext_vector_type(8)));
typedef unsigned short u16x4 __attribute__((ext_vector_type(4)));
typedef unsigned short u16x8 __attribute__((ext_vector_type(8)));

__device__ __forceinline__ unsigned short f2bf(float f) {
  unsigned u = __float_as_uint(f);
  u += 0x7fffu + ((u >> 16) & 1u);
  return (unsigned short)(u >> 16);
}
__device__ __forceinline__ float bf2f(unsigned short s) {
  return __uint_as_float(((unsigned)s) << 16);
}

// ---------------------------------------------------------------------------
// prep: w1,w2,w3 fp32 -> bf16 (layouts unchanged, K contiguous);
// w_r[br][tap][kt(16, zero-pad >=9)][c(128)] from w_cat (9,128,3,3)
// ---------------------------------------------------------------------------
__global__ void prep_kernel(const float* __restrict__ w1, const float* __restrict__ w2,
                            const float* __restrict__ w3,
                            const float* __restrict__ wa, const float* __restrict__ wb,
                            const float* __restrict__ wc, const float* __restrict__ wd,
                            unsigned short* __restrict__ w1b, unsigned short* __restrict__ w2b,
                            unsigned short* __restrict__ w3b, unsigned short* __restrict__ wr) {
  int idx = blockIdx.x * 256 + threadIdx.x;
  if (idx < 65536) { w1b[idx] = f2bf(w1[idx]); }
  else if (idx < 147456) { int j = idx - 65536; w2b[j] = f2bf(w2[j]); }
  else if (idx < 212992) { int j = idx - 147456; w3b[j] = f2bf(w3[j]); }
  else if (idx < 286720) {
    int j = idx - 212992;
    int br = j / 18432, rem = j % 18432;
    int tap = rem / 2048, rem2 = rem % 2048;
    int kt = rem2 / 128, c = rem2 % 128;
    const float* w = (br == 0) ? wa : (br == 1) ? wb : (br == 2) ? wc : wd;
    float v = (kt < 9) ? w[(kt * 128 + c) * 9 + tap] : 0.f;
    wr[j] = f2bf(v);
  }
}

// ---------------------------------------------------------------------------
// x (n,512,HW) fp32 -> x_t (n,HW,512) bf16, LDS-tiled 64x64 transpose
// ---------------------------------------------------------------------------
__global__ __launch_bounds__(256) void xcvt_kernel(const float* __restrict__ x,
                                                   unsigned short* __restrict__ xt) {
  __shared__ float lds[64 * 65];
  int tp = blockIdx.x, tc = blockIdx.y, n = blockIdx.z;
  int t = threadIdx.x;
  const float* xb = x + ((size_t)n * 512 + tc * 64) * HW + tp * 64;
#pragma unroll
  for (int rr = 0; rr < 4; ++rr) {
    int cl = rr * 16 + (t >> 4);
    int pl = (t & 15) * 4;
    float4 v = *(const float4*)(xb + (size_t)cl * HW + pl);
    lds[cl * 65 + pl + 0] = v.x; lds[cl * 65 + pl + 1] = v.y;
    lds[cl * 65 + pl + 2] = v.z; lds[cl * 65 + pl + 3] = v.w;
  }
  __syncthreads();
  unsigned short* xo = xt + ((size_t)n * HW + tp * 64) * 512 + tc * 64;
#pragma unroll
  for (int rr = 0; rr < 4; ++rr) {
    int pl = rr * 16 + (t >> 4);
    int cl = (t & 15) * 4;
    u16x4 o;
    o[0] = f2bf(lds[(cl + 0) * 65 + pl]); o[1] = f2bf(lds[(cl + 1) * 65 + pl]);
    o[2] = f2bf(lds[(cl + 2) * 65 + pl]); o[3] = f2bf(lds[(cl + 3) * 65 + pl]);
    *(u16x4*)(xo + (size_t)pl * 512 + cl) = o;
  }
}

// ---------------------------------------------------------------------------
// conv1/conv2 MFMA: act (n,HW,K) bf16 x W (128,K) bf16 -> out (n,HW,128) fp32
// ---------------------------------------------------------------------------
template<int K>
__global__ __launch_bounds__(256) void conv_pm_kernel(
    const unsigned short* __restrict__ act, const unsigned short* __restrict__ w,
    float* __restrict__ out) {
  int wv = threadIdx.x >> 6, lane = threadIdx.x & 63;
  int lr = lane & 15, lg = lane >> 4;
  int n = blockIdx.y;
  int p0 = blockIdx.x * 128 + wv * 32;
  const unsigned short* an = act + (size_t)n * HW * K;
  f32x4 acc[2][8];
#pragma unroll
  for (int pr = 0; pr < 2; ++pr)
#pragma unroll
    for (int cb = 0; cb < 8; ++cb) acc[pr][cb] = (f32x4){0.f, 0.f, 0.f, 0.f};
  const unsigned short* a0p = an + (size_t)(p0 + lr) * K + lg * 8;
  const unsigned short* a1p = an + (size_t)(p0 + 16 + lr) * K + lg * 8;
  const unsigned short* bp = w + (size_t)lr * K + lg * 8;
  for (int ks = 0; ks < K / 32; ++ks) {
    bf16x8 a0 = *(const bf16x8*)(a0p + ks * 32);
    bf16x8 a1 = *(const bf16x8*)(a1p + ks * 32);
#pragma unroll
    for (int cb = 0; cb < 8; ++cb) {
      bf16x8 b = *(const bf16x8*)(bp + (size_t)cb * 16 * K + ks * 32);
      acc[0][cb] = __builtin_amdgcn_mfma_f32_16x16x32_bf16(a0, b, acc[0][cb], 0, 0, 0);
      acc[1][cb] = __builtin_amdgcn_mfma_f32_16x16x32_bf16(a1, b, acc[1][cb], 0, 0, 0);
    }
  }
  float* on = out + (size_t)n * HW * 128;
#pragma unroll
  for (int pr = 0; pr < 2; ++pr)
#pragma unroll
    for (int cb = 0; cb < 8; ++cb)
#pragma unroll
      for (int r = 0; r < 4; ++r)
        on[(size_t)(p0 + pr * 16 + lg * 4 + r) * 128 + cb * 16 + lr] = acc[pr][cb][r];
}

// ---------------------------------------------------------------------------
// conv3 MFMA: W3 (512,128) x y2b (n,HW,128) -> out (n,512,HW) fp32 channel-major
// + fused GN3 partial sums
// ---------------------------------------------------------------------------
__global__ __launch_bounds__(256) void conv3_kernel(
    const unsigned short* __restrict__ y, const unsigned short* __restrict__ w3,
    float* __restrict__ out, float* __restrict__ part) {
  int wv = threadIdx.x >> 6, lane = threadIdx.x & 63;
  int lr = lane & 15, lg = lane >> 4;
  int n = blockIdx.y, zc = blockIdx.z;
  int co0 = zc * 128 + wv * 32;
  int p0 = blockIdx.x * 128;
  const unsigned short* yn = y + (size_t)n * HW * 128;
  f32x4 acc[2][8];
#pragma unroll
  for (int pr = 0; pr < 2; ++pr)
#pragma unroll
    for (int cb = 0; cb < 8; ++cb) acc[pr][cb] = (f32x4){0.f, 0.f, 0.f, 0.f};
#pragma unroll
  for (int ks = 0; ks < 4; ++ks) {
    bf16x8 a0 = *(const bf16x8*)(w3 + (size_t)(co0 + lr) * 128 + ks * 32 + lg * 8);
    bf16x8 a1 = *(const bf16x8*)(w3 + (size_t)(co0 + 16 + lr) * 128 + ks * 32 + lg * 8);
#pragma unroll
    for (int cb = 0; cb < 8; ++cb) {
      bf16x8 b = *(const bf16x8*)(yn + (size_t)(p0 + cb * 16 + lr) * 128 + ks * 32 + lg * 8);
      acc[0][cb] = __builtin_amdgcn_mfma_f32_16x16x32_bf16(a0, b, acc[0][cb], 0, 0, 0);
      acc[1][cb] = __builtin_amdgcn_mfma_f32_16x16x32_bf16(a1, b, acc[1][cb], 0, 0, 0);
    }
  }
  float* on = out + (size_t)n * 512 * HW;
  float s[2] = {0.f, 0.f}, ss[2] = {0.f, 0.f};
#pragma unroll
  for (int pr = 0; pr < 2; ++pr)
#pragma unroll
    for (int cb = 0; cb < 8; ++cb)
#pragma unroll
      for (int r = 0; r < 4; ++r) {
        float v = acc[pr][cb][r];
        on[(size_t)(co0 + pr * 16 + lg * 4 + r) * HW + p0 + cb * 16 + lr] = v;
        s[pr] += v; ss[pr] += v * v;
      }
#pragma unroll
  for (int pr = 0; pr < 2; ++pr) {
    float a = s[pr], b = ss[pr];
    for (int m = 1; m < 64; m <<= 1) { a += __shfl_xor(a, m); b += __shfl_xor(b, m); }
    if (lane == 0) {
      float* pp = part + ((((size_t)n * 4 + zc) * 128 + blockIdx.x) * 8 + wv * 2 + pr) * 2;
      pp[0] = a; pp[1] = b;
    }
  }
}

__global__ void gnf3_kernel(const float* __restrict__ part, float* __restrict__ stats) {
  int t = threadIdx.x;
  int n = t >> 5, g = t & 31;
  int zc = g >> 3, sub = g & 7;
  float s = 0.f, ss = 0.f;
  for (int xb = 0; xb < 128; ++xb) {
    const float* pp = part + ((((size_t)n * 4 + zc) * 128 + xb) * 8 + sub) * 2;
    s += pp[0]; ss += pp[1];
  }
  float inv = 1.f / (16.f * HW);
  float mean = s * inv, var = ss * inv - mean * mean;
  stats[2 * t] = mean; stats[2 * t + 1] = rsqrtf(var + 1e-5f);
}

// ---------------------------------------------------------------------------
// GN stats (pixel-major, C=128, G=32, cpg=4)
// ---------------------------------------------------------------------------
__global__ __launch_bounds__(256) void gnp_pm_kernel(const float* __restrict__ src,
                                                     float* __restrict__ part) {
  int t = threadIdx.x;
  int g = t & 31, ph = t >> 5;
  int pt = blockIdx.x, n = blockIdx.y;
  const float* b = src + (size_t)n * HW * 128 + 4 * g;
  float s = 0.f, ss = 0.f;
  for (int p = pt * 2048 + ph; p < (pt + 1) * 2048; p += 8) {
    float4 v = *(const float4*)(b + (size_t)p * 128);
    s += v.x + v.y + v.z + v.w;
    ss += v.x * v.x + v.y * v.y + v.z * v.z + v.w * v.w;
  }
  __shared__ float sh[256], sh2[256];
  sh[t] = s; sh2[t] = ss; __syncthreads();
  if (t < 128) { sh[t] += sh[t + 128]; sh2[t] += sh2[t + 128]; } __syncthreads();
  if (t < 64)  { sh[t] += sh[t + 64];  sh2[t] += sh2[t + 64];  } __syncthreads();
  if (t < 32) {
    float a = sh[t] + sh[t + 32], b2 = sh2[t] + sh2[t + 32];
    float* pp = part + ((size_t)(n * 8 + pt) * 32 + t) * 2;
    pp[0] = a; pp[1] = b2;
  }
}

__global__ void gnf_pm_kernel(const float* __restrict__ part, float* __restrict__ stats) {
  int t = threadIdx.x;
  int n = t >> 5, g = t & 31;
  float s = 0.f, ss = 0.f;
#pragma unroll
  for (int pt = 0; pt < 8; ++pt) {
    const float* pp = part + ((size_t)(n * 8 + pt) * 32 + g) * 2;
    s += pp[0]; ss += pp[1];
  }
  float inv = 1.f / (4.f * HW);
  float mean = s * inv, var = ss * inv - mean * mean;
  stats[2 * t] = mean; stats[2 * t + 1] = rsqrtf(var + 1e-5f);
}

// GN apply (pixel-major) + ReLU -> bf16 dst with row stride ldd
__global__ __launch_bounds__(256) void gna_pm_kernel(
    const float* __restrict__ src, const float* __restrict__ stats,
    const float* __restrict__ gamma, const float* __restrict__ beta,
    unsigned short* __restrict__ dst, int ldd) {
  int idx = blockIdx.x * 256 + threadIdx.x;
  int g = idx & 31;
  int p = (idx >> 5) & (HW - 1);
  int n = idx >> 19;
  float4 v = *(const float4*)(src + ((size_t)n * HW + p) * 128 + 4 * g);
  int sg = n * 32 + g;
  float mean = stats[2 * sg], rstd = stats[2 * sg + 1];
  float sc0 = rstd * gamma[4 * g + 0], sc1 = rstd * gamma[4 * g + 1];
  float sc2 = rstd * gamma[4 * g + 2], sc3 = rstd * gamma[4 * g + 3];
  float sh0 = beta[4 * g + 0] - mean * sc0, sh1 = beta[4 * g + 1] - mean * sc1;
  float sh2 = beta[4 * g + 2] - mean * sc2, sh3 = beta[4 * g + 3] - mean * sc3;
  u16x4 o;
  o[0] = f2bf(fmaxf(fmaf(v.x, sc0, sh0), 0.f));
  o[1] = f2bf(fmaxf(fmaf(v.y, sc1, sh1), 0.f));
  o[2] = f2bf(fmaxf(fmaf(v.z, sc2, sh2), 0.f));
  o[3] = f2bf(fmaxf(fmaf(v.w, sc3, sh3), 0.f));
  *(u16x4*)(dst + ((size_t)n * HW + p) * ldd + 4 * g) = o;
}

// GN apply channel-major fp32 in place (stage 3)
__global__ __launch_bounds__(256) void gn_apply_kernel(
    float* __restrict__ t, const float* __restrict__ stats,
    const float* __restrict__ gamma, const float* __restrict__ beta,
    int C, int chPerG) {
  unsigned i4 = blockIdx.x * 256u + threadIdx.x;
  unsigned e = i4 * 4u;
  unsigned c = (e >> 14) % (unsigned)C;
  unsigned n = e / ((unsigned)C * HW);
  unsigned g = c / (unsigned)chPerG;
  unsigned sg = n * 32u + g;
  float mean = stats[2 * sg], rstd = stats[2 * sg + 1];
  float scale = rstd * gamma[c];
  float shift = beta[c] - mean * scale;
  float4* tp = (float4*)t;
  float4 v = tp[i4];
  v.x = fmaxf(fmaf(v.x, scale, shift), 0.f);
  v.y = fmaxf(fmaf(v.y, scale, shift), 0.f);
  v.z = fmaxf(fmaf(v.z, scale, shift), 0.f);
  v.w = fmaxf(fmaf(v.w, scale, shift), 0.f);
  tp[i4] = v;
}

// ---------------------------------------------------------------------------
// dynfused2: one block = one image row (128 px) of one (n, branch).
// Stage the 3 rows (h-d, h, h+d) in LDS (pitch-padded); MFMA filter conv +
// softmax + 9-tap apply all read LDS. 512 threads.
// LDS: 3*128*272 B rows + [128][17] f32 f = 113152 B.
// ---------------------------------------------------------------------------
#define DPITCH 136  // u16 units per px row slot (272 B)

__global__ __launch_bounds__(512) void dynfused2_kernel(
    const unsigned short* __restrict__ cat, const unsigned short* __restrict__ wr,
    unsigned short* __restrict__ catw) {
  extern __shared__ char smem[];
  unsigned short* rowbuf = (unsigned short*)smem;            // 3 * 128 * DPITCH u16
  float* fl = (float*)(smem + 3 * 128 * DPITCH * 2);         // [128][17] f32
  int t = threadIdx.x;
  int bid = blockIdx.x;
  int row = ((bid & 7) << 4) + (bid >> 3);     // XCD band swizzle
  int n = blockIdx.y >> 2, br = blockIdx.y & 3;
  int d = (br == 0) ? 1 : 4 * br;
  const unsigned short* xb = cat + (size_t)n * HW * 640;

  // stage 3 rows (clamped; invalid taps masked at use)
  int rg0 = max(row - d, 0), rg2 = min(row + d, 127);
  int rg[3] = { rg0, row, rg2 };
  for (int ci = t; ci < 3 * 2048; ci += 512) {
    int s = ci >> 11, rem = ci & 2047;
    int px = rem >> 4, c = rem & 15;
    u16x8 v = *(const u16x8*)(xb + ((size_t)(rg[s] * 128 + px)) * 640 + c * 8);
    *(u16x8*)(rowbuf + (size_t)s * 128 * DPITCH + px * DPITCH + c * 8) = v;
  }
  __syncthreads();

  bool rv[3] = { row - d >= 0, true, row + d < 128 };

  // filter conv via MFMA: wave wv -> px tile [wv*16, wv*16+16)
  {
    int wv = t >> 6, lane = t & 63;
    int lr = lane & 15, lg = lane >> 4;
    const unsigned short* wb = wr + (size_t)br * 9 * 16 * 128;
    const bf16x8 zb = {(__bf16)0.f, (__bf16)0.f, (__bf16)0.f, (__bf16)0.f,
                       (__bf16)0.f, (__bf16)0.f, (__bf16)0.f, (__bf16)0.f};
    f32x4 acc = (f32x4){0.f, 0.f, 0.f, 0.f};
    int pxA = wv * 16 + lr;
#pragma unroll
    for (int tap = 0; tap < 9; ++tap) {
      int s = tap / 3;
      int dw = (tap % 3 - 1) * d;
      int cw = pxA + dw;
      bool val = rv[s] && ((unsigned)cw < 128u);
      int cwc = min(max(cw, 0), 127);
      const unsigned short* ap = rowbuf + (size_t)s * 128 * DPITCH + cwc * DPITCH + lg * 8;
      const unsigned short* wt = wb + (size_t)(tap * 16 + lr) * 128 + lg * 8;
#pragma unroll
      for (int ks = 0; ks < 4; ++ks) {
        bf16x8 a = *(const bf16x8*)(ap + ks * 32);
        if (!val) a = zb;
        bf16x8 b = *(const bf16x8*)(wt + ks * 32);
        acc = __builtin_amdgcn_mfma_f32_16x16x32_bf16(a, b, acc, 0, 0, 0);
      }
    }
    // softmax over kt cols 0..8 within each 16-lane group
#pragma unroll
    for (int r = 0; r < 4; ++r) {
      float v = acc[r];
      float m = (lr < 9) ? v : -3.0e38f;
#pragma unroll
      for (int msk = 1; msk < 16; msk <<= 1) m = fmaxf(m, __shfl_xor(m, msk));
      float e = (lr < 9) ? expf(v - m) : 0.f;
      float su = e;
#pragma unroll
      for (int msk = 1; msk < 16; msk <<= 1) su += __shfl_xor(su, msk);
      fl[(wv * 16 + lg * 4 + r) * 17 + lr] = e / su;
    }
  }
  __syncthreads();

  // apply: thread (px = t>>2, c4 = t&3) accumulates 32 channels of pixel px
  {
    int px = t >> 2, c4 = t & 3;
    float oacc[32];
#pragma unroll
    for (int i = 0; i < 32; ++i) oacc[i] = 0.f;
#pragma unroll
    for (int tap = 0; tap < 9; ++tap) {
      int s = tap / 3;
      int dw = (tap % 3 - 1) * d;
      int cw = px + dw;
      bool val = rv[s] && ((unsigned)cw < 128u);
      float f = val ? fl[px * 17 + tap] : 0.f;
      int cwc = min(max(cw, 0), 127);
      const unsigned short* ap = rowbuf + (size_t)s * 128 * DPITCH + cwc * DPITCH + c4 * 32;
#pragma unroll
      for (int cc = 0; cc < 4; ++cc) {
        u16x8 u = *(const u16x8*)(ap + cc * 8);
#pragma unroll
        for (int i = 0; i < 8; ++i)
          oacc[cc * 8 + i] = fmaf(f, bf2f(u[i]), oacc[cc * 8 + i]);
      }
    }
    unsigned short* orow = catw + ((size_t)n * HW + row * 128 + px) * 640
                           + 128 * (br + 1) + c4 * 32;
#pragma unroll
    for (int cc = 0; cc < 4; ++cc) {
      u16x8 o;
#pragma unroll
      for (int i = 0; i < 8; ++i) o[i] = f2bf(oacc[cc * 8 + i]);
      *(u16x8*)(orow + cc * 8) = o;
    }
  }
}

// ---------------------------------------------------------------------------
extern "C" void kernel_launch(void* const* d_in, const int* in_sizes, int n_in,
                              void* d_out, int out_size, void* d_ws, size_t ws_size,
                              hipStream_t stream) {
  const float* x   = (const float*)d_in[0];
  const float* w1  = (const float*)d_in[1];
  const float* g1  = (const float*)d_in[2];
  const float* b1  = (const float*)d_in[3];
  const float* wca = (const float*)d_in[4];
  const float* wcb = (const float*)d_in[5];
  const float* wcc = (const float*)d_in[6];
  const float* wcd = (const float*)d_in[7];
  const float* w2  = (const float*)d_in[8];
  const float* g2  = (const float*)d_in[9];
  const float* b2  = (const float*)d_in[10];
  const float* w3  = (const float*)d_in[11];
  const float* g3  = (const float*)d_in[12];
  const float* b3  = (const float*)d_in[13];
  float* out = (float*)d_out;

  float* ws = (float*)d_ws;
  unsigned short* xt  = (unsigned short*)ws;               // [0,16M) f: x_t bf16
  float* xd_t = ws + 16777216;                             // [16M,24M) fp32 (n,HW,128)
  unsigned short* cat = (unsigned short*)(ws + 25165824);  // [24M,44M): (n,HW,640) bf16
  float* y2t = ws;                                         // [0,8M) fp32 (overlay x_t)
  unsigned short* y2b = (unsigned short*)(ws + 8388608);   // [8M,12M) bf16
  float* aux = ws + 46137344;
  unsigned short* w1b = (unsigned short*)(aux);
  unsigned short* w2b = (unsigned short*)(aux + 32768);
  unsigned short* w3b = (unsigned short*)(aux + 73728);
  unsigned short* wr  = (unsigned short*)(aux + 106496);
  float* part  = aux + 143360;
  float* part3 = aux + 145408;
  float* st1   = aux + 178176;
  float* st2   = aux + 178432;
  float* st3   = aux + 178688;

  dim3 blk(256);
  const int dynLds = 3 * 128 * DPITCH * 2 + 128 * 17 * 4;  // 113152 B
  (void)hipFuncSetAttribute((const void*)dynfused2_kernel,
                            hipFuncAttributeMaxDynamicSharedMemorySize, dynLds);

  prep_kernel<<<dim3(1120), blk, 0, stream>>>(w1, w2, w3, wca, wcb, wcc, wcd,
                                              w1b, w2b, w3b, wr);
  xcvt_kernel<<<dim3(256, 8, 4), blk, 0, stream>>>(x, xt);

  // stage 1: conv 512->128 (MFMA), GN, ReLU -> cat cols 0..127 (bf16)
  conv_pm_kernel<512><<<dim3(128, 4), blk, 0, stream>>>(xt, w1b, xd_t);
  gnp_pm_kernel<<<dim3(8, 4), blk, 0, stream>>>(xd_t, part);
  gnf_pm_kernel<<<dim3(1), dim3(128), 0, stream>>>(part, st1);
  gna_pm_kernel<<<dim3(8192), blk, 0, stream>>>(xd_t, st1, g1, b1, cat, 640);

  // four fused dynamic branches -> cat cols 128..639 (bf16)
  dynfused2_kernel<<<dim3(128, 16), dim3(512), dynLds, stream>>>(cat, wr, cat);

  // stage 2: conv 640->128 (MFMA) over concat, GN, ReLU -> y2b bf16
  conv_pm_kernel<640><<<dim3(128, 4), blk, 0, stream>>>(cat, w2b, y2t);
  gnp_pm_kernel<<<dim3(8, 4), blk, 0, stream>>>(y2t, part);
  gnf_pm_kernel<<<dim3(1), dim3(128), 0, stream>>>(part, st2);
  gna_pm_kernel<<<dim3(8192), blk, 0, stream>>>(y2t, st2, g2, b2, y2b, 128);

  // stage 3: conv 128->512 (MFMA) -> d_out channel-major + fused GN3 partials
  conv3_kernel<<<dim3(128, 4, 4), blk, 0, stream>>>(y2b, w3b, out, part3);
  gnf3_kernel<<<dim3(1), dim3(128), 0, stream>>>(part3, st3);
  gn_apply_kernel<<<dim3(32768), blk, 0, stream>>>(out, st3, g3, b3, 512, 16);
}